// Round 5
// baseline (1440.725 us; speedup 1.0000x reference)
//
#include <hip/hip_runtime.h>
#include <math.h>

#define NN 131072
#define EE 2097152
#define ET (EE + NN)
#define GG 512
#define BN_EPS 1e-5f

// ---------------- CSR build ----------------
// hist: in-degree count + per-dst edge-attr sums (for self-loop mean attrs)
__global__ void k_hist(const int* __restrict__ ei, const float* __restrict__ ea,
                       int* __restrict__ cnt, float* __restrict__ s0,
                       float* __restrict__ s1, float* __restrict__ s2) {
  int e = blockIdx.x * blockDim.x + threadIdx.x;
  if (e >= EE) return;
  int d = ei[EE + e];
  atomicAdd(&cnt[d], 1);
  atomicAdd(&s0[d], ea[3 * e]);
  atomicAdd(&s1[d], ea[3 * e + 1]);
  atomicAdd(&s2[d], ea[3 * e + 2]);
}

__global__ void k_scan_a(const int* __restrict__ cnt, int* __restrict__ off_out,
                         int* __restrict__ bsum) {
  __shared__ int s[256];
  int i = blockIdx.x * 256 + threadIdx.x;
  int x = cnt[i] + 1;  // +1 self loop
  s[threadIdx.x] = x;
  __syncthreads();
#pragma unroll
  for (int o = 1; o < 256; o <<= 1) {
    int t = (threadIdx.x >= o) ? s[threadIdx.x - o] : 0;
    __syncthreads();
    s[threadIdx.x] += t;
    __syncthreads();
  }
  off_out[i] = s[threadIdx.x] - x;  // exclusive within block
  if (threadIdx.x == 255) bsum[blockIdx.x] = s[255];
}

__global__ void k_scan_b(int* __restrict__ bsum) {
  __shared__ int s[512];
  int t = threadIdx.x;
  int x = bsum[t];
  s[t] = x;
  __syncthreads();
#pragma unroll
  for (int o = 1; o < 512; o <<= 1) {
    int v = (t >= o) ? s[t - o] : 0;
    __syncthreads();
    s[t] += v;
    __syncthreads();
  }
  bsum[t] = s[t] - x;  // exclusive, in place
}

__global__ void k_scan_c(int* __restrict__ off_out, const int* __restrict__ bsum) {
  int i = blockIdx.x * 256 + threadIdx.x;
  off_out[i] += bsum[blockIdx.x];
  if (i == 0) off_out[NN] = ET;
}

// packed slot: {ea0, ea1, ea2, src-as-int-bits} — single 16B store per edge
__global__ void k_scatter(const int* __restrict__ ei, const float* __restrict__ ea,
                          const int* __restrict__ off, int* __restrict__ cur,
                          float4* __restrict__ ces) {
  int e = blockIdx.x * blockDim.x + threadIdx.x;
  if (e >= EE) return;
  int s = ei[e], d = ei[EE + e];
  int p = off[d] + atomicAdd(&cur[d], 1);
  float4 t = {ea[3 * e], ea[3 * e + 1], ea[3 * e + 2], __int_as_float(s)};
  ces[p] = t;
}

// self-loop slot = last slot of each node; attrs = mean of incoming (from hist sums)
__global__ void k_selfslot(const int* __restrict__ off, const float* __restrict__ s0,
                           const float* __restrict__ s1, const float* __restrict__ s2,
                           float4* __restrict__ ces) {
  int v = blockIdx.x * blockDim.x + threadIdx.x;
  if (v >= NN) return;
  int b = off[v];
  int d = off[v + 1] - b - 1;  // real in-degree
  float inv = 1.0f / (float)(d > 0 ? d : 1);
  float4 t = {s0[v] * inv, s1[v] * inv, s2[v] * inv, __int_as_float(v)};
  ces[b + d] = t;
}

// ---------------- node linear: xl = f(x)@wl+bl ; xr = f(x)@wr+br ----------------
template <int K, int O, bool DO_BN>
__global__ void k_lin(const float* __restrict__ x, const float* __restrict__ wl,
                      const float* __restrict__ bl, const float* __restrict__ wr,
                      const float* __restrict__ br, float* __restrict__ xl,
                      float* __restrict__ xr, const float* __restrict__ bnsum,
                      const float* __restrict__ bnss, const float* __restrict__ g,
                      const float* __restrict__ be) {
  constexpr int NPB = 256 / O;  // nodes per block-iteration
  __shared__ float swl[K * O], swr[K * O], sx[NPB * K];
  __shared__ float sscale[K], sshift[K];
  for (int i = threadIdx.x; i < K * O; i += 256) {
    swl[i] = wl[i];
    swr[i] = wr[i];
  }
  if (DO_BN && threadIdx.x < K) {
    int c = threadIdx.x;
    float mu = bnsum[c] * (1.0f / NN);
    float var = bnss[c] * (1.0f / NN) - mu * mu;
    float is = rsqrtf(var + BN_EPS) * g[c];
    sscale[c] = is;
    sshift[c] = be[c] - mu * is;
  }
  int o = threadIdx.x % O;
  int ln = threadIdx.x / O;
  float blv = bl[o], brv = br[o];
  __syncthreads();
  for (int v0 = blockIdx.x * NPB; v0 < NN; v0 += gridDim.x * NPB) {
    __syncthreads();
    for (int i = threadIdx.x; i < NPB * K; i += 256) {
      float xv = x[(size_t)v0 * K + i];
      if (DO_BN) {
        int c = i & (K - 1);
        xv = xv * sscale[c] + sshift[c];
        xv = (xv > 0.0f) ? xv : (__expf(xv) - 1.0f);
      }
      sx[i] = xv;
    }
    __syncthreads();
    float al = blv, ar = brv;
#pragma unroll 8
    for (int k = 0; k < K; k++) {
      float xv = sx[ln * K + k];
      al += xv * swl[k * O + o];
      ar += xv * swr[k * O + o];
    }
    int v = v0 + ln;
    xl[(size_t)v * O + o] = al;
    xr[(size_t)v * O + o] = ar;
  }
}

// ---------------- fused GATv2 edge phase ----------------
// One wave per node. 32 channel-lanes (cl = lane&31) cover all HC channels via
// vector loads; lane halves process 2 edge streams. 4 edges per iteration
// (2 pairs), 2-stage pipeline: rows for group g+1 and packed attrs+src for
// group g+2 are in flight while computing group g. The per-edge dot reduce is
// 4 shuffle steps shared by 2 edges (halves reduce independently, masks<32,
// within-16 groups per head). No running max (validated R2-R4).

// HC=128: float4/lane; head0 = cl 0..15 (ch 4cl..4cl+3), head1 = cl 16..31.
__global__ void k_gat128(const int* __restrict__ off, const float4* __restrict__ ces,
                         const float4* __restrict__ xl, const float4* __restrict__ xr,
                         const float4* __restrict__ we, const float4* __restrict__ att,
                         const float4* __restrict__ bias, float4* __restrict__ hout,
                         float* __restrict__ bnsum, float* __restrict__ bnss) {
  __shared__ float lsum[4][64], lsq[4][64];
  int lane = threadIdx.x & 63;
  int wid = threadIdx.x >> 6;
  int cl = lane & 31;
  int half = lane >> 5;
  const float4 w0 = we[cl], w1 = we[32 + cl], w2 = we[64 + cl];
  const float4 av = att[cl];
  float4 rs = {0, 0, 0, 0}, rq = {0, 0, 0, 0};
  for (int v = blockIdx.x * 4 + wid; v < NN; v += gridDim.x * 4) {
    int b = off[v], e = off[v + 1];
    int last = e - 1;
    float4 xrv = xr[(size_t)v * 32 + cl];
    float ssum = 0.0f;
    float4 acc = {0, 0, 0, 0};
    int ng = (e - b + 3) >> 2;
    int j = b;
    // prologue: group0 packed+rows, group1 packed
    float4 pa = ces[min(j + half, last)];
    float4 pb = ces[min(j + 2 + half, last)];
    float4 ra = xl[(size_t)__float_as_int(pa.w) * 32 + cl];
    float4 rb = xl[(size_t)__float_as_int(pb.w) * 32 + cl];
    float4 qa = ces[min(j + 4 + half, last)];
    float4 qb = ces[min(j + 6 + half, last)];
    for (int g = 0; g < ng; g++, j += 4) {
      float4 nra = xl[(size_t)__float_as_int(qa.w) * 32 + cl];
      float4 nrb = xl[(size_t)__float_as_int(qb.w) * 32 + cl];
      float4 ta = ces[min(j + 8 + half, last)];
      float4 tb = ces[min(j + 10 + half, last)];
      float4 ma, mb;
      ma.x = ra.x + xrv.x + pa.x * w0.x + pa.y * w1.x + pa.z * w2.x;
      ma.y = ra.y + xrv.y + pa.x * w0.y + pa.y * w1.y + pa.z * w2.y;
      ma.z = ra.z + xrv.z + pa.x * w0.z + pa.y * w1.z + pa.z * w2.z;
      ma.w = ra.w + xrv.w + pa.x * w0.w + pa.y * w1.w + pa.z * w2.w;
      mb.x = rb.x + xrv.x + pb.x * w0.x + pb.y * w1.x + pb.z * w2.x;
      mb.y = rb.y + xrv.y + pb.x * w0.y + pb.y * w1.y + pb.z * w2.y;
      mb.z = rb.z + xrv.z + pb.x * w0.z + pb.y * w1.z + pb.z * w2.z;
      mb.w = rb.w + xrv.w + pb.x * w0.w + pb.y * w1.w + pb.z * w2.w;
      ma.x = fmaxf(ma.x, 0.2f * ma.x); ma.y = fmaxf(ma.y, 0.2f * ma.y);
      ma.z = fmaxf(ma.z, 0.2f * ma.z); ma.w = fmaxf(ma.w, 0.2f * ma.w);
      mb.x = fmaxf(mb.x, 0.2f * mb.x); mb.y = fmaxf(mb.y, 0.2f * mb.y);
      mb.z = fmaxf(mb.z, 0.2f * mb.z); mb.w = fmaxf(mb.w, 0.2f * mb.w);
      float la = ma.x * av.x + ma.y * av.y + ma.z * av.z + ma.w * av.w;
      float lb = mb.x * av.x + mb.y * av.y + mb.z * av.z + mb.w * av.w;
#pragma unroll
      for (int m = 1; m <= 8; m <<= 1) {  // per-head reduce (16-lane groups)
        la += __shfl_xor(la, m, 64);
        lb += __shfl_xor(lb, m, 64);
      }
      float pA = ((j + half) < e) ? __expf(la) : 0.0f;
      float pB = ((j + 2 + half) < e) ? __expf(lb) : 0.0f;
      ssum += pA + pB;
      acc.x += pA * ra.x + pB * rb.x;
      acc.y += pA * ra.y + pB * rb.y;
      acc.z += pA * ra.z + pB * rb.z;
      acc.w += pA * ra.w + pB * rb.w;
      pa = qa; pb = qb; ra = nra; rb = nrb; qa = ta; qb = tb;
    }
    // combine the two edge streams
    ssum += __shfl_xor(ssum, 32, 64);
    acc.x += __shfl_xor(acc.x, 32, 64);
    acc.y += __shfl_xor(acc.y, 32, 64);
    acc.z += __shfl_xor(acc.z, 32, 64);
    acc.w += __shfl_xor(acc.w, 32, 64);
    float inv = 1.0f / (ssum + 1e-16f);
    float4 o = {acc.x * inv, acc.y * inv, acc.z * inv, acc.w * inv};
    // head mean: partner cl^16 holds the other head's same channel slot
    float px = __shfl_xor(o.x, 16, 64);
    float py = __shfl_xor(o.y, 16, 64);
    float pz = __shfl_xor(o.z, 16, 64);
    float pw = __shfl_xor(o.w, 16, 64);
    if (lane < 16) {
      float4 bv = bias[lane];
      float4 val = {0.5f * (o.x + px) + bv.x, 0.5f * (o.y + py) + bv.y,
                    0.5f * (o.z + pz) + bv.z, 0.5f * (o.w + pw) + bv.w};
      hout[(size_t)v * 16 + lane] = val;
      rs.x += val.x; rs.y += val.y; rs.z += val.z; rs.w += val.w;
      rq.x += val.x * val.x; rq.y += val.y * val.y;
      rq.z += val.z * val.z; rq.w += val.w * val.w;
    }
  }
  if (lane < 16) {
    lsum[wid][4 * lane] = rs.x; lsum[wid][4 * lane + 1] = rs.y;
    lsum[wid][4 * lane + 2] = rs.z; lsum[wid][4 * lane + 3] = rs.w;
    lsq[wid][4 * lane] = rq.x; lsq[wid][4 * lane + 1] = rq.y;
    lsq[wid][4 * lane + 2] = rq.z; lsq[wid][4 * lane + 3] = rq.w;
  }
  __syncthreads();
  if (threadIdx.x < 64) {
    float a = lsum[0][threadIdx.x] + lsum[1][threadIdx.x] + lsum[2][threadIdx.x] +
              lsum[3][threadIdx.x];
    float q = lsq[0][threadIdx.x] + lsq[1][threadIdx.x] + lsq[2][threadIdx.x] +
              lsq[3][threadIdx.x];
    atomicAdd(&bnsum[threadIdx.x], a);
    atomicAdd(&bnss[threadIdx.x], q);
  }
}

// HC=64: float2/lane; head0 = cl 0..15 (ch 2cl..2cl+1), head1 = cl 16..31.
__global__ void k_gat64(const int* __restrict__ off, const float4* __restrict__ ces,
                        const float2* __restrict__ xl, const float2* __restrict__ xr,
                        const float2* __restrict__ we, const float2* __restrict__ att,
                        const float2* __restrict__ bias, float2* __restrict__ hout,
                        float* __restrict__ bnsum, float* __restrict__ bnss) {
  __shared__ float lsum[4][32], lsq[4][32];
  int lane = threadIdx.x & 63;
  int wid = threadIdx.x >> 6;
  int cl = lane & 31;
  int half = lane >> 5;
  const float2 w0 = we[cl], w1 = we[32 + cl], w2 = we[64 + cl];
  const float2 av = att[cl];
  float2 rs = {0, 0}, rq = {0, 0};
  for (int v = blockIdx.x * 4 + wid; v < NN; v += gridDim.x * 4) {
    int b = off[v], e = off[v + 1];
    int last = e - 1;
    float2 xrv = xr[(size_t)v * 32 + cl];
    float ssum = 0.0f;
    float2 acc = {0, 0};
    int ng = (e - b + 3) >> 2;
    int j = b;
    float4 pa = ces[min(j + half, last)];
    float4 pb = ces[min(j + 2 + half, last)];
    float2 ra = xl[(size_t)__float_as_int(pa.w) * 32 + cl];
    float2 rb = xl[(size_t)__float_as_int(pb.w) * 32 + cl];
    float4 qa = ces[min(j + 4 + half, last)];
    float4 qb = ces[min(j + 6 + half, last)];
    for (int g = 0; g < ng; g++, j += 4) {
      float2 nra = xl[(size_t)__float_as_int(qa.w) * 32 + cl];
      float2 nrb = xl[(size_t)__float_as_int(qb.w) * 32 + cl];
      float4 ta = ces[min(j + 8 + half, last)];
      float4 tb = ces[min(j + 10 + half, last)];
      float2 ma, mb;
      ma.x = ra.x + xrv.x + pa.x * w0.x + pa.y * w1.x + pa.z * w2.x;
      ma.y = ra.y + xrv.y + pa.x * w0.y + pa.y * w1.y + pa.z * w2.y;
      mb.x = rb.x + xrv.x + pb.x * w0.x + pb.y * w1.x + pb.z * w2.x;
      mb.y = rb.y + xrv.y + pb.x * w0.y + pb.y * w1.y + pb.z * w2.y;
      ma.x = fmaxf(ma.x, 0.2f * ma.x); ma.y = fmaxf(ma.y, 0.2f * ma.y);
      mb.x = fmaxf(mb.x, 0.2f * mb.x); mb.y = fmaxf(mb.y, 0.2f * mb.y);
      float la = ma.x * av.x + ma.y * av.y;
      float lb = mb.x * av.x + mb.y * av.y;
#pragma unroll
      for (int m = 1; m <= 8; m <<= 1) {
        la += __shfl_xor(la, m, 64);
        lb += __shfl_xor(lb, m, 64);
      }
      float pA = ((j + half) < e) ? __expf(la) : 0.0f;
      float pB = ((j + 2 + half) < e) ? __expf(lb) : 0.0f;
      ssum += pA + pB;
      acc.x += pA * ra.x + pB * rb.x;
      acc.y += pA * ra.y + pB * rb.y;
      pa = qa; pb = qb; ra = nra; rb = nrb; qa = ta; qb = tb;
    }
    ssum += __shfl_xor(ssum, 32, 64);
    acc.x += __shfl_xor(acc.x, 32, 64);
    acc.y += __shfl_xor(acc.y, 32, 64);
    float inv = 1.0f / (ssum + 1e-16f);
    float2 o = {acc.x * inv, acc.y * inv};
    float px = __shfl_xor(o.x, 16, 64);
    float py = __shfl_xor(o.y, 16, 64);
    if (lane < 16) {
      float2 bv = bias[lane];
      float2 val = {0.5f * (o.x + px) + bv.x, 0.5f * (o.y + py) + bv.y};
      hout[(size_t)v * 16 + lane] = val;
      rs.x += val.x; rs.y += val.y;
      rq.x += val.x * val.x; rq.y += val.y * val.y;
    }
  }
  if (lane < 16) {
    lsum[wid][2 * lane] = rs.x; lsum[wid][2 * lane + 1] = rs.y;
    lsq[wid][2 * lane] = rq.x; lsq[wid][2 * lane + 1] = rq.y;
  }
  __syncthreads();
  if (threadIdx.x < 32) {
    float a = lsum[0][threadIdx.x] + lsum[1][threadIdx.x] + lsum[2][threadIdx.x] +
              lsum[3][threadIdx.x];
    float q = lsq[0][threadIdx.x] + lsq[1][threadIdx.x] + lsq[2][threadIdx.x] +
              lsq[3][threadIdx.x];
    atomicAdd(&bnsum[threadIdx.x], a);
    atomicAdd(&bnss[threadIdx.x], q);
  }
}

// ---------------- pooling (fused BN2+ELU) + head ----------------
__global__ void k_gcount(const int* __restrict__ batch, int* __restrict__ gcount) {
  int v = blockIdx.x * blockDim.x + threadIdx.x;
  if (v < NN) atomicAdd(&gcount[batch[v]], 1);
}

__global__ void k_goff(const int* __restrict__ gcount, int* __restrict__ goff) {
  __shared__ int s[GG];
  int t = threadIdx.x;
  int x = gcount[t];
  s[t] = x;
  __syncthreads();
#pragma unroll
  for (int o = 1; o < GG; o <<= 1) {
    int v = (t >= o) ? s[t - o] : 0;
    __syncthreads();
    s[t] += v;
    __syncthreads();
  }
  goff[t] = s[t] - x;
}

__global__ void k_pool(const float* __restrict__ h2, const int* __restrict__ goff,
                       const int* __restrict__ gcount, const float* __restrict__ bnsum,
                       const float* __restrict__ bnss, const float* __restrict__ g,
                       const float* __restrict__ be, float* __restrict__ pooled) {
  int gi = blockIdx.x, c = threadIdx.x;  // 64 threads
  float mu = bnsum[c] * (1.0f / NN);
  float var = bnss[c] * (1.0f / NN) - mu * mu;
  float is = rsqrtf(var + BN_EPS) * g[c];
  float sh = be[c] - mu * is;
  int s = goff[gi], n = gcount[gi];
  float acc = 0.0f;
  int i = 0;
  for (; i + 4 <= n; i += 4) {  // 4 independent loads in flight
    float y0 = h2[(size_t)(s + i) * 64 + c];
    float y1 = h2[(size_t)(s + i + 1) * 64 + c];
    float y2 = h2[(size_t)(s + i + 2) * 64 + c];
    float y3 = h2[(size_t)(s + i + 3) * 64 + c];
    y0 = y0 * is + sh; y1 = y1 * is + sh; y2 = y2 * is + sh; y3 = y3 * is + sh;
    y0 = (y0 > 0.0f) ? y0 : (__expf(y0) - 1.0f);
    y1 = (y1 > 0.0f) ? y1 : (__expf(y1) - 1.0f);
    y2 = (y2 > 0.0f) ? y2 : (__expf(y2) - 1.0f);
    y3 = (y3 > 0.0f) ? y3 : (__expf(y3) - 1.0f);
    acc += (y0 + y1) + (y2 + y3);
  }
  for (; i < n; i++) {
    float y = h2[(size_t)(s + i) * 64 + c] * is + sh;
    y = (y > 0.0f) ? y : (__expf(y) - 1.0f);
    acc += y;
  }
  pooled[gi * 64 + c] = acc / fmaxf((float)n, 1.0f);
}

__global__ void k_fc1(const float* __restrict__ pooled, const float* __restrict__ w,
                      const float* __restrict__ b, float* __restrict__ t1) {
  int i = blockIdx.x * blockDim.x + threadIdx.x;  // 16384
  int g = i >> 5, o = i & 31;
  float acc = b[o];
#pragma unroll 8
  for (int k = 0; k < 64; k++) acc += pooled[g * 64 + k] * w[k * 32 + o];
  t1[i] = acc;
}

__global__ void k_head(const float* __restrict__ t1, const float* __restrict__ g3,
                       const float* __restrict__ be3, const float* __restrict__ fc2w,
                       const float* __restrict__ fc2b, float* __restrict__ out) {
  __shared__ float ssum[32], ssq[32], smu[32], sinv[32];
  int t = threadIdx.x;  // 512 threads, one per graph
  if (t < 32) {
    ssum[t] = 0.0f;
    ssq[t] = 0.0f;
  }
  __syncthreads();
  float y[32];
#pragma unroll
  for (int o = 0; o < 32; o++) y[o] = t1[t * 32 + o];
#pragma unroll
  for (int o = 0; o < 32; o++) {
    atomicAdd(&ssum[o], y[o]);
    atomicAdd(&ssq[o], y[o] * y[o]);
  }
  __syncthreads();
  if (t < 32) {
    float mu = ssum[t] * (1.0f / GG);
    float var = ssq[t] * (1.0f / GG) - mu * mu;
    smu[t] = mu;
    sinv[t] = rsqrtf(var + BN_EPS);
  }
  __syncthreads();
  float acc = fc2b[0];
#pragma unroll
  for (int o = 0; o < 32; o++) {
    float yy = (y[o] - smu[o]) * sinv[o] * g3[o] + be3[o];
    yy = (yy > 0.0f) ? yy : (__expf(yy) - 1.0f);
    acc += yy * fc2w[o];
  }
  out[t] = 1.0f / (1.0f + __expf(-acc));
}

// ---------------- launch ----------------
extern "C" void kernel_launch(void* const* d_in, const int* in_sizes, int n_in,
                              void* d_out, int out_size, void* d_ws, size_t ws_size,
                              hipStream_t stream) {
  const float* x = (const float*)d_in[0];
  const float* ea = (const float*)d_in[1];
  const float* w1l = (const float*)d_in[2];
  const float* b1l = (const float*)d_in[3];
  const float* w1r = (const float*)d_in[4];
  const float* b1r = (const float*)d_in[5];
  const float* w1e = (const float*)d_in[6];
  const float* att1 = (const float*)d_in[7];
  const float* bias1 = (const float*)d_in[8];
  const float* g1 = (const float*)d_in[9];
  const float* be1 = (const float*)d_in[10];
  const float* w2l = (const float*)d_in[11];
  const float* b2l = (const float*)d_in[12];
  const float* w2r = (const float*)d_in[13];
  const float* b2r = (const float*)d_in[14];
  const float* w2e = (const float*)d_in[15];
  const float* att2 = (const float*)d_in[16];
  const float* bias2 = (const float*)d_in[17];
  const float* g2 = (const float*)d_in[18];
  const float* be2 = (const float*)d_in[19];
  const float* fc1w = (const float*)d_in[20];
  const float* fc1b = (const float*)d_in[21];
  const float* g3 = (const float*)d_in[22];
  const float* be3 = (const float*)d_in[23];
  const float* fc2w = (const float*)d_in[24];
  const float* fc2b = (const float*)d_in[25];
  const int* ei = (const int*)d_in[26];
  const int* batch = (const int*)d_in[27];
  float* out = (float*)d_out;

  char* w = (char*)d_ws;
  size_t off = 0;
  auto alloc = [&](size_t bytes) {
    size_t r = off;
    off += (bytes + 255) & ~(size_t)255;
    return r;
  };
  // zero-init region (one memset)
  int* cnt = (int*)(w + alloc(NN * 4));
  int* cur = (int*)(w + alloc(NN * 4));
  int* gcount = (int*)(w + alloc(GG * 4));
  float* eas0 = (float*)(w + alloc(NN * 4));
  float* eas1 = (float*)(w + alloc(NN * 4));
  float* eas2 = (float*)(w + alloc(NN * 4));
  float* bn1sum = (float*)(w + alloc(32 * 4));
  float* bn1ss = (float*)(w + alloc(32 * 4));
  float* bn2sum = (float*)(w + alloc(64 * 4));
  float* bn2ss = (float*)(w + alloc(64 * 4));
  size_t zero_bytes = off;
  // rest
  int* csr_off = (int*)(w + alloc((size_t)(NN + 1) * 4));
  int* bsum = (int*)(w + alloc(512 * 4));
  int* goff = (int*)(w + alloc((size_t)(GG + 1) * 4));
  float4* ces = (float4*)(w + alloc((size_t)ET * 16));
  float* xl = (float*)(w + alloc((size_t)NN * 128 * 4));
  float* xr = (float*)(w + alloc((size_t)NN * 128 * 4));
  float* h1 = (float*)(w + alloc((size_t)NN * 32 * 4));
  float* h2 = (float*)(w + alloc((size_t)NN * 64 * 4));
  float* pooled = (float*)(w + alloc((size_t)GG * 64 * 4));
  float* t1 = (float*)(w + alloc((size_t)GG * 32 * 4));
  (void)ws_size;
  (void)in_sizes;
  (void)n_in;
  (void)out_size;

  hipMemsetAsync(d_ws, 0, zero_bytes, stream);

  // CSR build
  k_hist<<<EE / 256, 256, 0, stream>>>(ei, ea, cnt, eas0, eas1, eas2);
  k_scan_a<<<512, 256, 0, stream>>>(cnt, csr_off, bsum);
  k_scan_b<<<1, 512, 0, stream>>>(bsum);
  k_scan_c<<<512, 256, 0, stream>>>(csr_off, bsum);
  k_scatter<<<EE / 256, 256, 0, stream>>>(ei, ea, csr_off, cur, ces);
  k_selfslot<<<NN / 256, 256, 0, stream>>>(csr_off, eas0, eas1, eas2, ces);

  // layer 1 (HC=64, C=32)
  k_lin<64, 64, false><<<2048, 256, 0, stream>>>(x, w1l, b1l, w1r, b1r, xl, xr,
                                                 nullptr, nullptr, nullptr, nullptr);
  k_gat64<<<2048, 256, 0, stream>>>(csr_off, ces, (const float2*)xl,
                                    (const float2*)xr, (const float2*)w1e,
                                    (const float2*)att1, (const float2*)bias1,
                                    (float2*)h1, bn1sum, bn1ss);

  // layer 2 (HC=128, C=64) — BN1+ELU fused into the staging load
  k_lin<32, 128, true><<<2048, 256, 0, stream>>>(h1, w2l, b2l, w2r, b2r, xl, xr,
                                                 bn1sum, bn1ss, g1, be1);
  k_gat128<<<2048, 256, 0, stream>>>(csr_off, ces, (const float4*)xl,
                                     (const float4*)xr, (const float4*)w2e,
                                     (const float4*)att2, (const float4*)bias2,
                                     (float4*)h2, bn2sum, bn2ss);

  // pooling (BN2+ELU fused) + head
  k_gcount<<<NN / 256, 256, 0, stream>>>(batch, gcount);
  k_goff<<<1, GG, 0, stream>>>(gcount, goff);
  k_pool<<<GG, 64, 0, stream>>>(h2, goff, gcount, bn2sum, bn2ss, g2, be2, pooled);
  k_fc1<<<64, 256, 0, stream>>>(pooled, fc1w, fc1b, t1);
  k_head<<<1, GG, 0, stream>>>(t1, g3, be3, fc2w, fc2b, out);
}

// Round 6
// 1149.057 us; speedup vs baseline: 1.2538x; 1.2538x over previous
//
#include <hip/hip_runtime.h>
#include <math.h>

#define NN 131072
#define EE 2097152
#define ET (EE + NN)
#define GG 512
#define BN_EPS 1e-5f

// ---------------- CSR build ----------------
__global__ void k_hist(const int* __restrict__ ei, int* __restrict__ cnt) {
  int e = blockIdx.x * blockDim.x + threadIdx.x;
  if (e < EE) atomicAdd(&cnt[ei[EE + e]], 1);
}

__global__ void k_scan_a(const int* __restrict__ cnt, int* __restrict__ off_out,
                         int* __restrict__ bsum) {
  __shared__ int s[256];
  int i = blockIdx.x * 256 + threadIdx.x;
  int x = cnt[i] + 1;  // +1 self loop
  s[threadIdx.x] = x;
  __syncthreads();
#pragma unroll
  for (int o = 1; o < 256; o <<= 1) {
    int t = (threadIdx.x >= o) ? s[threadIdx.x - o] : 0;
    __syncthreads();
    s[threadIdx.x] += t;
    __syncthreads();
  }
  off_out[i] = s[threadIdx.x] - x;  // exclusive within block
  if (threadIdx.x == 255) bsum[blockIdx.x] = s[255];
}

__global__ void k_scan_b(int* __restrict__ bsum) {
  __shared__ int s[512];
  int t = threadIdx.x;
  int x = bsum[t];
  s[t] = x;
  __syncthreads();
#pragma unroll
  for (int o = 1; o < 512; o <<= 1) {
    int v = (t >= o) ? s[t - o] : 0;
    __syncthreads();
    s[t] += v;
    __syncthreads();
  }
  bsum[t] = s[t] - x;  // exclusive, in place
}

__global__ void k_scan_c(int* __restrict__ off_out, const int* __restrict__ bsum) {
  int i = blockIdx.x * 256 + threadIdx.x;
  off_out[i] += bsum[blockIdx.x];
  if (i == 0) off_out[NN] = ET;
}

// packed slot: {ea0, ea1, ea2, src-as-int-bits} — single 16B store per edge
__global__ void k_scatter(const int* __restrict__ ei, const float* __restrict__ ea,
                          const int* __restrict__ off, int* __restrict__ cur,
                          float4* __restrict__ ces) {
  int e = blockIdx.x * blockDim.x + threadIdx.x;
  if (e >= EE) return;
  int s = ei[e], d = ei[EE + e];
  int p = off[d] + atomicAdd(&cur[d], 1);
  float4 t = {ea[3 * e], ea[3 * e + 1], ea[3 * e + 2], __int_as_float(s)};
  ces[p] = t;
}

// self-loop slot = last slot of each node; attrs = mean of that node's incoming
// real-edge attrs (sequential sweep over its packed CSR segment).
__global__ void k_selfslot(const int* __restrict__ off, float4* __restrict__ ces) {
  int v = blockIdx.x * blockDim.x + threadIdx.x;
  if (v >= NN) return;
  int b = off[v];
  int d = off[v + 1] - b - 1;  // real in-degree
  float s0 = 0.f, s1 = 0.f, s2 = 0.f;
  int j = b;
  for (; j + 4 <= b + d; j += 4) {
    float4 t0 = ces[j], t1 = ces[j + 1], t2 = ces[j + 2], t3 = ces[j + 3];
    s0 += (t0.x + t1.x) + (t2.x + t3.x);
    s1 += (t0.y + t1.y) + (t2.y + t3.y);
    s2 += (t0.z + t1.z) + (t2.z + t3.z);
  }
  for (; j < b + d; j++) {
    float4 t = ces[j];
    s0 += t.x;
    s1 += t.y;
    s2 += t.z;
  }
  float inv = 1.0f / (float)(d > 0 ? d : 1);
  float4 t = {s0 * inv, s1 * inv, s2 * inv, __int_as_float(v)};
  ces[b + d] = t;
}

// ---------------- node linear: xl = f(x)@wl+bl ; xr = f(x)@wr+br ----------------
template <int K, int O, bool DO_BN>
__global__ void k_lin(const float* __restrict__ x, const float* __restrict__ wl,
                      const float* __restrict__ bl, const float* __restrict__ wr,
                      const float* __restrict__ br, float* __restrict__ xl,
                      float* __restrict__ xr, const float* __restrict__ bnsum,
                      const float* __restrict__ bnss, const float* __restrict__ g,
                      const float* __restrict__ be) {
  constexpr int NPB = 256 / O;  // nodes per block-iteration
  __shared__ float swl[K * O], swr[K * O], sx[NPB * K];
  __shared__ float sscale[K], sshift[K];
  for (int i = threadIdx.x; i < K * O; i += 256) {
    swl[i] = wl[i];
    swr[i] = wr[i];
  }
  if (DO_BN && threadIdx.x < K) {
    int c = threadIdx.x;
    float mu = bnsum[c] * (1.0f / NN);
    float var = bnss[c] * (1.0f / NN) - mu * mu;
    float is = rsqrtf(var + BN_EPS) * g[c];
    sscale[c] = is;
    sshift[c] = be[c] - mu * is;
  }
  int o = threadIdx.x % O;
  int ln = threadIdx.x / O;
  float blv = bl[o], brv = br[o];
  __syncthreads();
  for (int v0 = blockIdx.x * NPB; v0 < NN; v0 += gridDim.x * NPB) {
    __syncthreads();
    for (int i = threadIdx.x; i < NPB * K; i += 256) {
      float xv = x[(size_t)v0 * K + i];
      if (DO_BN) {
        int c = i & (K - 1);
        xv = xv * sscale[c] + sshift[c];
        xv = (xv > 0.0f) ? xv : (__expf(xv) - 1.0f);
      }
      sx[i] = xv;
    }
    __syncthreads();
    float al = blv, ar = brv;
#pragma unroll 8
    for (int k = 0; k < K; k++) {
      float xv = sx[ln * K + k];
      al += xv * swl[k * O + o];
      ar += xv * swr[k * O + o];
    }
    int v = v0 + ln;
    xl[(size_t)v * O + o] = al;
    xr[(size_t)v * O + o] = ar;
  }
}

// ---------------- fused GATv2 edge phase ----------------
// One wave per node. 32 channel-lanes (cl = lane&31) cover all HC channels via
// vector loads; lane halves process 2 edge streams. 4 edges per iteration
// (2 pairs), 2-stage pipeline: rows for group g+1 and packed attrs+src for
// group g+2 are in flight while computing group g. The per-edge dot reduce is
// 4 shuffle steps shared by 2 edges (halves reduce independently, masks<32,
// within-16 groups per head). No running max (validated R2-R5).

// HC=128: float4/lane; head0 = cl 0..15 (ch 4cl..4cl+3), head1 = cl 16..31.
__global__ void k_gat128(const int* __restrict__ off, const float4* __restrict__ ces,
                         const float4* __restrict__ xl, const float4* __restrict__ xr,
                         const float4* __restrict__ we, const float4* __restrict__ att,
                         const float4* __restrict__ bias, float4* __restrict__ hout,
                         float* __restrict__ bnsum, float* __restrict__ bnss) {
  __shared__ float lsum[4][64], lsq[4][64];
  int lane = threadIdx.x & 63;
  int wid = threadIdx.x >> 6;
  int cl = lane & 31;
  int half = lane >> 5;
  const float4 w0 = we[cl], w1 = we[32 + cl], w2 = we[64 + cl];
  const float4 av = att[cl];
  float4 rs = {0, 0, 0, 0}, rq = {0, 0, 0, 0};
  for (int v = blockIdx.x * 4 + wid; v < NN; v += gridDim.x * 4) {
    int b = off[v], e = off[v + 1];
    int last = e - 1;
    float4 xrv = xr[(size_t)v * 32 + cl];
    float ssum = 0.0f;
    float4 acc = {0, 0, 0, 0};
    int ng = (e - b + 3) >> 2;
    int j = b;
    // prologue: group0 packed+rows, group1 packed
    float4 pa = ces[min(j + half, last)];
    float4 pb = ces[min(j + 2 + half, last)];
    float4 ra = xl[(size_t)__float_as_int(pa.w) * 32 + cl];
    float4 rb = xl[(size_t)__float_as_int(pb.w) * 32 + cl];
    float4 qa = ces[min(j + 4 + half, last)];
    float4 qb = ces[min(j + 6 + half, last)];
    for (int g = 0; g < ng; g++, j += 4) {
      float4 nra = xl[(size_t)__float_as_int(qa.w) * 32 + cl];
      float4 nrb = xl[(size_t)__float_as_int(qb.w) * 32 + cl];
      float4 ta = ces[min(j + 8 + half, last)];
      float4 tb = ces[min(j + 10 + half, last)];
      float4 ma, mb;
      ma.x = ra.x + xrv.x + pa.x * w0.x + pa.y * w1.x + pa.z * w2.x;
      ma.y = ra.y + xrv.y + pa.x * w0.y + pa.y * w1.y + pa.z * w2.y;
      ma.z = ra.z + xrv.z + pa.x * w0.z + pa.y * w1.z + pa.z * w2.z;
      ma.w = ra.w + xrv.w + pa.x * w0.w + pa.y * w1.w + pa.z * w2.w;
      mb.x = rb.x + xrv.x + pb.x * w0.x + pb.y * w1.x + pb.z * w2.x;
      mb.y = rb.y + xrv.y + pb.x * w0.y + pb.y * w1.y + pb.z * w2.y;
      mb.z = rb.z + xrv.z + pb.x * w0.z + pb.y * w1.z + pb.z * w2.z;
      mb.w = rb.w + xrv.w + pb.x * w0.w + pb.y * w1.w + pb.z * w2.w;
      ma.x = fmaxf(ma.x, 0.2f * ma.x); ma.y = fmaxf(ma.y, 0.2f * ma.y);
      ma.z = fmaxf(ma.z, 0.2f * ma.z); ma.w = fmaxf(ma.w, 0.2f * ma.w);
      mb.x = fmaxf(mb.x, 0.2f * mb.x); mb.y = fmaxf(mb.y, 0.2f * mb.y);
      mb.z = fmaxf(mb.z, 0.2f * mb.z); mb.w = fmaxf(mb.w, 0.2f * mb.w);
      float la = ma.x * av.x + ma.y * av.y + ma.z * av.z + ma.w * av.w;
      float lb = mb.x * av.x + mb.y * av.y + mb.z * av.z + mb.w * av.w;
#pragma unroll
      for (int m = 1; m <= 8; m <<= 1) {  // per-head reduce (16-lane groups)
        la += __shfl_xor(la, m, 64);
        lb += __shfl_xor(lb, m, 64);
      }
      float pA = ((j + half) < e) ? __expf(la) : 0.0f;
      float pB = ((j + 2 + half) < e) ? __expf(lb) : 0.0f;
      ssum += pA + pB;
      acc.x += pA * ra.x + pB * rb.x;
      acc.y += pA * ra.y + pB * rb.y;
      acc.z += pA * ra.z + pB * rb.z;
      acc.w += pA * ra.w + pB * rb.w;
      pa = qa; pb = qb; ra = nra; rb = nrb; qa = ta; qb = tb;
    }
    // combine the two edge streams
    ssum += __shfl_xor(ssum, 32, 64);
    acc.x += __shfl_xor(acc.x, 32, 64);
    acc.y += __shfl_xor(acc.y, 32, 64);
    acc.z += __shfl_xor(acc.z, 32, 64);
    acc.w += __shfl_xor(acc.w, 32, 64);
    float inv = 1.0f / (ssum + 1e-16f);
    float4 o = {acc.x * inv, acc.y * inv, acc.z * inv, acc.w * inv};
    // head mean: partner cl^16 holds the other head's same channel slot
    float px = __shfl_xor(o.x, 16, 64);
    float py = __shfl_xor(o.y, 16, 64);
    float pz = __shfl_xor(o.z, 16, 64);
    float pw = __shfl_xor(o.w, 16, 64);
    if (lane < 16) {
      float4 bv = bias[lane];
      float4 val = {0.5f * (o.x + px) + bv.x, 0.5f * (o.y + py) + bv.y,
                    0.5f * (o.z + pz) + bv.z, 0.5f * (o.w + pw) + bv.w};
      hout[(size_t)v * 16 + lane] = val;
      rs.x += val.x; rs.y += val.y; rs.z += val.z; rs.w += val.w;
      rq.x += val.x * val.x; rq.y += val.y * val.y;
      rq.z += val.z * val.z; rq.w += val.w * val.w;
    }
  }
  if (lane < 16) {
    lsum[wid][4 * lane] = rs.x; lsum[wid][4 * lane + 1] = rs.y;
    lsum[wid][4 * lane + 2] = rs.z; lsum[wid][4 * lane + 3] = rs.w;
    lsq[wid][4 * lane] = rq.x; lsq[wid][4 * lane + 1] = rq.y;
    lsq[wid][4 * lane + 2] = rq.z; lsq[wid][4 * lane + 3] = rq.w;
  }
  __syncthreads();
  if (threadIdx.x < 64) {
    float a = lsum[0][threadIdx.x] + lsum[1][threadIdx.x] + lsum[2][threadIdx.x] +
              lsum[3][threadIdx.x];
    float q = lsq[0][threadIdx.x] + lsq[1][threadIdx.x] + lsq[2][threadIdx.x] +
              lsq[3][threadIdx.x];
    atomicAdd(&bnsum[threadIdx.x], a);
    atomicAdd(&bnss[threadIdx.x], q);
  }
}

// HC=64: float2/lane; head0 = cl 0..15 (ch 2cl..2cl+1), head1 = cl 16..31.
__global__ void k_gat64(const int* __restrict__ off, const float4* __restrict__ ces,
                        const float2* __restrict__ xl, const float2* __restrict__ xr,
                        const float2* __restrict__ we, const float2* __restrict__ att,
                        const float2* __restrict__ bias, float2* __restrict__ hout,
                        float* __restrict__ bnsum, float* __restrict__ bnss) {
  __shared__ float lsum[4][32], lsq[4][32];
  int lane = threadIdx.x & 63;
  int wid = threadIdx.x >> 6;
  int cl = lane & 31;
  int half = lane >> 5;
  const float2 w0 = we[cl], w1 = we[32 + cl], w2 = we[64 + cl];
  const float2 av = att[cl];
  float2 rs = {0, 0}, rq = {0, 0};
  for (int v = blockIdx.x * 4 + wid; v < NN; v += gridDim.x * 4) {
    int b = off[v], e = off[v + 1];
    int last = e - 1;
    float2 xrv = xr[(size_t)v * 32 + cl];
    float ssum = 0.0f;
    float2 acc = {0, 0};
    int ng = (e - b + 3) >> 2;
    int j = b;
    float4 pa = ces[min(j + half, last)];
    float4 pb = ces[min(j + 2 + half, last)];
    float2 ra = xl[(size_t)__float_as_int(pa.w) * 32 + cl];
    float2 rb = xl[(size_t)__float_as_int(pb.w) * 32 + cl];
    float4 qa = ces[min(j + 4 + half, last)];
    float4 qb = ces[min(j + 6 + half, last)];
    for (int g = 0; g < ng; g++, j += 4) {
      float2 nra = xl[(size_t)__float_as_int(qa.w) * 32 + cl];
      float2 nrb = xl[(size_t)__float_as_int(qb.w) * 32 + cl];
      float4 ta = ces[min(j + 8 + half, last)];
      float4 tb = ces[min(j + 10 + half, last)];
      float2 ma, mb;
      ma.x = ra.x + xrv.x + pa.x * w0.x + pa.y * w1.x + pa.z * w2.x;
      ma.y = ra.y + xrv.y + pa.x * w0.y + pa.y * w1.y + pa.z * w2.y;
      mb.x = rb.x + xrv.x + pb.x * w0.x + pb.y * w1.x + pb.z * w2.x;
      mb.y = rb.y + xrv.y + pb.x * w0.y + pb.y * w1.y + pb.z * w2.y;
      ma.x = fmaxf(ma.x, 0.2f * ma.x); ma.y = fmaxf(ma.y, 0.2f * ma.y);
      mb.x = fmaxf(mb.x, 0.2f * mb.x); mb.y = fmaxf(mb.y, 0.2f * mb.y);
      float la = ma.x * av.x + ma.y * av.y;
      float lb = mb.x * av.x + mb.y * av.y;
#pragma unroll
      for (int m = 1; m <= 8; m <<= 1) {
        la += __shfl_xor(la, m, 64);
        lb += __shfl_xor(lb, m, 64);
      }
      float pA = ((j + half) < e) ? __expf(la) : 0.0f;
      float pB = ((j + 2 + half) < e) ? __expf(lb) : 0.0f;
      ssum += pA + pB;
      acc.x += pA * ra.x + pB * rb.x;
      acc.y += pA * ra.y + pB * rb.y;
      pa = qa; pb = qb; ra = nra; rb = nrb; qa = ta; qb = tb;
    }
    ssum += __shfl_xor(ssum, 32, 64);
    acc.x += __shfl_xor(acc.x, 32, 64);
    acc.y += __shfl_xor(acc.y, 32, 64);
    float inv = 1.0f / (ssum + 1e-16f);
    float2 o = {acc.x * inv, acc.y * inv};
    float px = __shfl_xor(o.x, 16, 64);
    float py = __shfl_xor(o.y, 16, 64);
    if (lane < 16) {
      float2 bv = bias[lane];
      float2 val = {0.5f * (o.x + px) + bv.x, 0.5f * (o.y + py) + bv.y};
      hout[(size_t)v * 16 + lane] = val;
      rs.x += val.x; rs.y += val.y;
      rq.x += val.x * val.x; rq.y += val.y * val.y;
    }
  }
  if (lane < 16) {
    lsum[wid][2 * lane] = rs.x; lsum[wid][2 * lane + 1] = rs.y;
    lsq[wid][2 * lane] = rq.x; lsq[wid][2 * lane + 1] = rq.y;
  }
  __syncthreads();
  if (threadIdx.x < 32) {
    float a = lsum[0][threadIdx.x] + lsum[1][threadIdx.x] + lsum[2][threadIdx.x] +
              lsum[3][threadIdx.x];
    float q = lsq[0][threadIdx.x] + lsq[1][threadIdx.x] + lsq[2][threadIdx.x] +
              lsq[3][threadIdx.x];
    atomicAdd(&bnsum[threadIdx.x], a);
    atomicAdd(&bnss[threadIdx.x], q);
  }
}

// ---------------- pooling (fused BN2+ELU) + head ----------------
__global__ void k_gcount(const int* __restrict__ batch, int* __restrict__ gcount) {
  int v = blockIdx.x * blockDim.x + threadIdx.x;
  if (v < NN) atomicAdd(&gcount[batch[v]], 1);
}

__global__ void k_goff(const int* __restrict__ gcount, int* __restrict__ goff) {
  __shared__ int s[GG];
  int t = threadIdx.x;
  int x = gcount[t];
  s[t] = x;
  __syncthreads();
#pragma unroll
  for (int o = 1; o < GG; o <<= 1) {
    int v = (t >= o) ? s[t - o] : 0;
    __syncthreads();
    s[t] += v;
    __syncthreads();
  }
  goff[t] = s[t] - x;
}

__global__ void k_pool(const float* __restrict__ h2, const int* __restrict__ goff,
                       const int* __restrict__ gcount, const float* __restrict__ bnsum,
                       const float* __restrict__ bnss, const float* __restrict__ g,
                       const float* __restrict__ be, float* __restrict__ pooled) {
  int gi = blockIdx.x, c = threadIdx.x;  // 64 threads
  float mu = bnsum[c] * (1.0f / NN);
  float var = bnss[c] * (1.0f / NN) - mu * mu;
  float is = rsqrtf(var + BN_EPS) * g[c];
  float sh = be[c] - mu * is;
  int s = goff[gi], n = gcount[gi];
  float acc = 0.0f;
  int i = 0;
  for (; i + 4 <= n; i += 4) {  // 4 independent loads in flight
    float y0 = h2[(size_t)(s + i) * 64 + c];
    float y1 = h2[(size_t)(s + i + 1) * 64 + c];
    float y2 = h2[(size_t)(s + i + 2) * 64 + c];
    float y3 = h2[(size_t)(s + i + 3) * 64 + c];
    y0 = y0 * is + sh; y1 = y1 * is + sh; y2 = y2 * is + sh; y3 = y3 * is + sh;
    y0 = (y0 > 0.0f) ? y0 : (__expf(y0) - 1.0f);
    y1 = (y1 > 0.0f) ? y1 : (__expf(y1) - 1.0f);
    y2 = (y2 > 0.0f) ? y2 : (__expf(y2) - 1.0f);
    y3 = (y3 > 0.0f) ? y3 : (__expf(y3) - 1.0f);
    acc += (y0 + y1) + (y2 + y3);
  }
  for (; i < n; i++) {
    float y = h2[(size_t)(s + i) * 64 + c] * is + sh;
    y = (y > 0.0f) ? y : (__expf(y) - 1.0f);
    acc += y;
  }
  pooled[gi * 64 + c] = acc / fmaxf((float)n, 1.0f);
}

__global__ void k_fc1(const float* __restrict__ pooled, const float* __restrict__ w,
                      const float* __restrict__ b, float* __restrict__ t1) {
  int i = blockIdx.x * blockDim.x + threadIdx.x;  // 16384
  int g = i >> 5, o = i & 31;
  float acc = b[o];
#pragma unroll 8
  for (int k = 0; k < 64; k++) acc += pooled[g * 64 + k] * w[k * 32 + o];
  t1[i] = acc;
}

__global__ void k_head(const float* __restrict__ t1, const float* __restrict__ g3,
                       const float* __restrict__ be3, const float* __restrict__ fc2w,
                       const float* __restrict__ fc2b, float* __restrict__ out) {
  __shared__ float ssum[32], ssq[32], smu[32], sinv[32];
  int t = threadIdx.x;  // 512 threads, one per graph
  if (t < 32) {
    ssum[t] = 0.0f;
    ssq[t] = 0.0f;
  }
  __syncthreads();
  float y[32];
#pragma unroll
  for (int o = 0; o < 32; o++) y[o] = t1[t * 32 + o];
#pragma unroll
  for (int o = 0; o < 32; o++) {
    atomicAdd(&ssum[o], y[o]);
    atomicAdd(&ssq[o], y[o] * y[o]);
  }
  __syncthreads();
  if (t < 32) {
    float mu = ssum[t] * (1.0f / GG);
    float var = ssq[t] * (1.0f / GG) - mu * mu;
    smu[t] = mu;
    sinv[t] = rsqrtf(var + BN_EPS);
  }
  __syncthreads();
  float acc = fc2b[0];
#pragma unroll
  for (int o = 0; o < 32; o++) {
    float yy = (y[o] - smu[o]) * sinv[o] * g3[o] + be3[o];
    yy = (yy > 0.0f) ? yy : (__expf(yy) - 1.0f);
    acc += yy * fc2w[o];
  }
  out[t] = 1.0f / (1.0f + __expf(-acc));
}

// ---------------- launch ----------------
extern "C" void kernel_launch(void* const* d_in, const int* in_sizes, int n_in,
                              void* d_out, int out_size, void* d_ws, size_t ws_size,
                              hipStream_t stream) {
  const float* x = (const float*)d_in[0];
  const float* ea = (const float*)d_in[1];
  const float* w1l = (const float*)d_in[2];
  const float* b1l = (const float*)d_in[3];
  const float* w1r = (const float*)d_in[4];
  const float* b1r = (const float*)d_in[5];
  const float* w1e = (const float*)d_in[6];
  const float* att1 = (const float*)d_in[7];
  const float* bias1 = (const float*)d_in[8];
  const float* g1 = (const float*)d_in[9];
  const float* be1 = (const float*)d_in[10];
  const float* w2l = (const float*)d_in[11];
  const float* b2l = (const float*)d_in[12];
  const float* w2r = (const float*)d_in[13];
  const float* b2r = (const float*)d_in[14];
  const float* w2e = (const float*)d_in[15];
  const float* att2 = (const float*)d_in[16];
  const float* bias2 = (const float*)d_in[17];
  const float* g2 = (const float*)d_in[18];
  const float* be2 = (const float*)d_in[19];
  const float* fc1w = (const float*)d_in[20];
  const float* fc1b = (const float*)d_in[21];
  const float* g3 = (const float*)d_in[22];
  const float* be3 = (const float*)d_in[23];
  const float* fc2w = (const float*)d_in[24];
  const float* fc2b = (const float*)d_in[25];
  const int* ei = (const int*)d_in[26];
  const int* batch = (const int*)d_in[27];
  float* out = (float*)d_out;

  char* w = (char*)d_ws;
  size_t off = 0;
  auto alloc = [&](size_t bytes) {
    size_t r = off;
    off += (bytes + 255) & ~(size_t)255;
    return r;
  };
  // zero-init region (one memset)
  int* cnt = (int*)(w + alloc(NN * 4));
  int* cur = (int*)(w + alloc(NN * 4));
  int* gcount = (int*)(w + alloc(GG * 4));
  float* bn1sum = (float*)(w + alloc(32 * 4));
  float* bn1ss = (float*)(w + alloc(32 * 4));
  float* bn2sum = (float*)(w + alloc(64 * 4));
  float* bn2ss = (float*)(w + alloc(64 * 4));
  size_t zero_bytes = off;
  // rest
  int* csr_off = (int*)(w + alloc((size_t)(NN + 1) * 4));
  int* bsum = (int*)(w + alloc(512 * 4));
  int* goff = (int*)(w + alloc((size_t)(GG + 1) * 4));
  float4* ces = (float4*)(w + alloc((size_t)ET * 16));
  float* xl = (float*)(w + alloc((size_t)NN * 128 * 4));
  float* xr = (float*)(w + alloc((size_t)NN * 128 * 4));
  float* h1 = (float*)(w + alloc((size_t)NN * 32 * 4));
  float* h2 = (float*)(w + alloc((size_t)NN * 64 * 4));
  float* pooled = (float*)(w + alloc((size_t)GG * 64 * 4));
  float* t1 = (float*)(w + alloc((size_t)GG * 32 * 4));
  (void)ws_size;
  (void)in_sizes;
  (void)n_in;
  (void)out_size;

  hipMemsetAsync(d_ws, 0, zero_bytes, stream);

  // CSR build
  k_hist<<<EE / 256, 256, 0, stream>>>(ei, cnt);
  k_scan_a<<<512, 256, 0, stream>>>(cnt, csr_off, bsum);
  k_scan_b<<<1, 512, 0, stream>>>(bsum);
  k_scan_c<<<512, 256, 0, stream>>>(csr_off, bsum);
  k_scatter<<<EE / 256, 256, 0, stream>>>(ei, ea, csr_off, cur, ces);
  k_selfslot<<<NN / 256, 256, 0, stream>>>(csr_off, ces);

  // layer 1 (HC=64, C=32)
  k_lin<64, 64, false><<<2048, 256, 0, stream>>>(x, w1l, b1l, w1r, b1r, xl, xr,
                                                 nullptr, nullptr, nullptr, nullptr);
  k_gat64<<<2048, 256, 0, stream>>>(csr_off, ces, (const float2*)xl,
                                    (const float2*)xr, (const float2*)w1e,
                                    (const float2*)att1, (const float2*)bias1,
                                    (float2*)h1, bn1sum, bn1ss);

  // layer 2 (HC=128, C=64) — BN1+ELU fused into the staging load
  k_lin<32, 128, true><<<2048, 256, 0, stream>>>(h1, w2l, b2l, w2r, b2r, xl, xr,
                                                 bn1sum, bn1ss, g1, be1);
  k_gat128<<<2048, 256, 0, stream>>>(csr_off, ces, (const float4*)xl,
                                     (const float4*)xr, (const float4*)w2e,
                                     (const float4*)att2, (const float4*)bias2,
                                     (float4*)h2, bn2sum, bn2ss);

  // pooling (BN2+ELU fused) + head
  k_gcount<<<NN / 256, 256, 0, stream>>>(batch, gcount);
  k_goff<<<1, GG, 0, stream>>>(gcount, goff);
  k_pool<<<GG, 64, 0, stream>>>(h2, goff, gcount, bn2sum, bn2ss, g2, be2, pooled);
  k_fc1<<<64, 256, 0, stream>>>(pooled, fc1w, fc1b, t1);
  k_head<<<1, GG, 0, stream>>>(t1, g3, be3, fc2w, fc2b, out);
}

// Round 7
// 1010.733 us; speedup vs baseline: 1.4254x; 1.1369x over previous
//
#include <hip/hip_runtime.h>
#include <math.h>

#define NN 131072
#define EE 2097152
#define ET (EE + NN)
#define GG 512
#define BN_EPS 1e-5f

// ---------------- CSR build ----------------
// hist: in-degree count; atomic return value = within-node rank (reused by scatter)
__global__ void k_hist(const int* __restrict__ ei, int* __restrict__ cnt,
                       int* __restrict__ rank) {
  int e = blockIdx.x * blockDim.x + threadIdx.x;
  if (e >= EE) return;
  rank[e] = atomicAdd(&cnt[ei[EE + e]], 1);
}

__global__ void k_scan_a(const int* __restrict__ cnt, int* __restrict__ off_out,
                         int* __restrict__ bsum) {
  __shared__ int s[256];
  int i = blockIdx.x * 256 + threadIdx.x;
  int x = cnt[i] + 1;  // +1 self loop
  s[threadIdx.x] = x;
  __syncthreads();
#pragma unroll
  for (int o = 1; o < 256; o <<= 1) {
    int t = (threadIdx.x >= o) ? s[threadIdx.x - o] : 0;
    __syncthreads();
    s[threadIdx.x] += t;
    __syncthreads();
  }
  off_out[i] = s[threadIdx.x] - x;  // exclusive within block
  if (threadIdx.x == 255) bsum[blockIdx.x] = s[255];
}

__global__ void k_scan_b(int* __restrict__ bsum) {
  __shared__ int s[512];
  int t = threadIdx.x;
  int x = bsum[t];
  s[t] = x;
  __syncthreads();
#pragma unroll
  for (int o = 1; o < 512; o <<= 1) {
    int v = (t >= o) ? s[t - o] : 0;
    __syncthreads();
    s[t] += v;
    __syncthreads();
  }
  bsum[t] = s[t] - x;  // exclusive, in place
}

__global__ void k_scan_c(int* __restrict__ off_out, const int* __restrict__ bsum) {
  int i = blockIdx.x * 256 + threadIdx.x;
  off_out[i] += bsum[blockIdx.x];
  if (i == 0) off_out[NN] = ET;
}

// packed slot: {ea0, ea1, ea2, src-as-int-bits}; position from precomputed rank
__global__ void k_scatter(const int* __restrict__ ei, const float* __restrict__ ea,
                          const int* __restrict__ off, const int* __restrict__ rank,
                          float4* __restrict__ ces) {
  int e = blockIdx.x * blockDim.x + threadIdx.x;
  if (e >= EE) return;
  int s = ei[e], d = ei[EE + e];
  int p = off[d] + rank[e];
  float4 t = {ea[3 * e], ea[3 * e + 1], ea[3 * e + 2], __int_as_float(s)};
  ces[p] = t;
}

// self-loop slot = last slot of each node; attrs = mean of incoming real-edge
// attrs. Wave-cooperative: 4 nodes per wave, 16 lanes sweep each segment.
__global__ void k_selfslot(const int* __restrict__ off, float4* __restrict__ ces) {
  int tid = blockIdx.x * blockDim.x + threadIdx.x;
  int wave = tid >> 6;
  int lane = threadIdx.x & 63;
  int grp = lane >> 4;  // node sub-index within wave
  int gl = lane & 15;   // lane within 16-group
  int v = wave * 4 + grp;
  if (v >= NN) return;
  int b = off[v];
  int d = off[v + 1] - b - 1;  // real in-degree
  float s0 = 0.f, s1 = 0.f, s2 = 0.f;
  for (int j = gl; j < d; j += 16) {
    float4 t = ces[b + j];
    s0 += t.x;
    s1 += t.y;
    s2 += t.z;
  }
#pragma unroll
  for (int m = 1; m <= 8; m <<= 1) {  // reduce within 16-lane group
    s0 += __shfl_xor(s0, m, 64);
    s1 += __shfl_xor(s1, m, 64);
    s2 += __shfl_xor(s2, m, 64);
  }
  if (gl == 0) {
    float inv = 1.0f / (float)(d > 0 ? d : 1);
    float4 t = {s0 * inv, s1 * inv, s2 * inv, __int_as_float(v)};
    ces[b + d] = t;
  }
}

// ---------------- node linear: xl = f(x)@wl+bl ; xr = f(x)@wr+br ----------------
template <int K, int O, bool DO_BN>
__global__ void k_lin(const float* __restrict__ x, const float* __restrict__ wl,
                      const float* __restrict__ bl, const float* __restrict__ wr,
                      const float* __restrict__ br, float* __restrict__ xl,
                      float* __restrict__ xr, const float* __restrict__ bnsum,
                      const float* __restrict__ bnss, const float* __restrict__ g,
                      const float* __restrict__ be) {
  constexpr int NPB = 256 / O;  // nodes per block-iteration
  __shared__ float swl[K * O], swr[K * O], sx[NPB * K];
  __shared__ float sscale[K], sshift[K];
  for (int i = threadIdx.x; i < K * O; i += 256) {
    swl[i] = wl[i];
    swr[i] = wr[i];
  }
  if (DO_BN && threadIdx.x < K) {
    int c = threadIdx.x;
    float mu = bnsum[c] * (1.0f / NN);
    float var = bnss[c] * (1.0f / NN) - mu * mu;
    float is = rsqrtf(var + BN_EPS) * g[c];
    sscale[c] = is;
    sshift[c] = be[c] - mu * is;
  }
  int o = threadIdx.x % O;
  int ln = threadIdx.x / O;
  float blv = bl[o], brv = br[o];
  __syncthreads();
  for (int v0 = blockIdx.x * NPB; v0 < NN; v0 += gridDim.x * NPB) {
    __syncthreads();
    for (int i = threadIdx.x; i < NPB * K; i += 256) {
      float xv = x[(size_t)v0 * K + i];
      if (DO_BN) {
        int c = i & (K - 1);
        xv = xv * sscale[c] + sshift[c];
        xv = (xv > 0.0f) ? xv : (__expf(xv) - 1.0f);
      }
      sx[i] = xv;
    }
    __syncthreads();
    float al = blv, ar = brv;
#pragma unroll 8
    for (int k = 0; k < K; k++) {
      float xv = sx[ln * K + k];
      al += xv * swl[k * O + o];
      ar += xv * swr[k * O + o];
    }
    int v = v0 + ln;
    xl[(size_t)v * O + o] = al;
    xr[(size_t)v * O + o] = ar;
  }
}

// ---------------- fused GATv2 edge phase ----------------
// One wave per node. 32 channel-lanes (cl = lane&31) cover all HC channels via
// vector loads; lane halves process 2 edge streams. 4 edges per iteration
// (2 pairs), 2-stage pipeline. No running max (validated R2-R6).

// HC=128: float4/lane; head0 = cl 0..15 (ch 4cl..4cl+3), head1 = cl 16..31.
__global__ void k_gat128(const int* __restrict__ off, const float4* __restrict__ ces,
                         const float4* __restrict__ xl, const float4* __restrict__ xr,
                         const float4* __restrict__ we, const float4* __restrict__ att,
                         const float4* __restrict__ bias, float4* __restrict__ hout,
                         float* __restrict__ bnsum, float* __restrict__ bnss) {
  __shared__ float lsum[4][64], lsq[4][64];
  int lane = threadIdx.x & 63;
  int wid = threadIdx.x >> 6;
  int cl = lane & 31;
  int half = lane >> 5;
  const float4 w0 = we[cl], w1 = we[32 + cl], w2 = we[64 + cl];
  const float4 av = att[cl];
  float4 rs = {0, 0, 0, 0}, rq = {0, 0, 0, 0};
  for (int v = blockIdx.x * 4 + wid; v < NN; v += gridDim.x * 4) {
    int b = off[v], e = off[v + 1];
    int last = e - 1;
    float4 xrv = xr[(size_t)v * 32 + cl];
    float ssum = 0.0f;
    float4 acc = {0, 0, 0, 0};
    int ng = (e - b + 3) >> 2;
    int j = b;
    float4 pa = ces[min(j + half, last)];
    float4 pb = ces[min(j + 2 + half, last)];
    float4 ra = xl[(size_t)__float_as_int(pa.w) * 32 + cl];
    float4 rb = xl[(size_t)__float_as_int(pb.w) * 32 + cl];
    float4 qa = ces[min(j + 4 + half, last)];
    float4 qb = ces[min(j + 6 + half, last)];
    for (int g = 0; g < ng; g++, j += 4) {
      float4 nra = xl[(size_t)__float_as_int(qa.w) * 32 + cl];
      float4 nrb = xl[(size_t)__float_as_int(qb.w) * 32 + cl];
      float4 ta = ces[min(j + 8 + half, last)];
      float4 tb = ces[min(j + 10 + half, last)];
      float4 ma, mb;
      ma.x = ra.x + xrv.x + pa.x * w0.x + pa.y * w1.x + pa.z * w2.x;
      ma.y = ra.y + xrv.y + pa.x * w0.y + pa.y * w1.y + pa.z * w2.y;
      ma.z = ra.z + xrv.z + pa.x * w0.z + pa.y * w1.z + pa.z * w2.z;
      ma.w = ra.w + xrv.w + pa.x * w0.w + pa.y * w1.w + pa.z * w2.w;
      mb.x = rb.x + xrv.x + pb.x * w0.x + pb.y * w1.x + pb.z * w2.x;
      mb.y = rb.y + xrv.y + pb.x * w0.y + pb.y * w1.y + pb.z * w2.y;
      mb.z = rb.z + xrv.z + pb.x * w0.z + pb.y * w1.z + pb.z * w2.z;
      mb.w = rb.w + xrv.w + pb.x * w0.w + pb.y * w1.w + pb.z * w2.w;
      ma.x = fmaxf(ma.x, 0.2f * ma.x); ma.y = fmaxf(ma.y, 0.2f * ma.y);
      ma.z = fmaxf(ma.z, 0.2f * ma.z); ma.w = fmaxf(ma.w, 0.2f * ma.w);
      mb.x = fmaxf(mb.x, 0.2f * mb.x); mb.y = fmaxf(mb.y, 0.2f * mb.y);
      mb.z = fmaxf(mb.z, 0.2f * mb.z); mb.w = fmaxf(mb.w, 0.2f * mb.w);
      float la = ma.x * av.x + ma.y * av.y + ma.z * av.z + ma.w * av.w;
      float lb = mb.x * av.x + mb.y * av.y + mb.z * av.z + mb.w * av.w;
#pragma unroll
      for (int m = 1; m <= 8; m <<= 1) {  // per-head reduce (16-lane groups)
        la += __shfl_xor(la, m, 64);
        lb += __shfl_xor(lb, m, 64);
      }
      float pA = ((j + half) < e) ? __expf(la) : 0.0f;
      float pB = ((j + 2 + half) < e) ? __expf(lb) : 0.0f;
      ssum += pA + pB;
      acc.x += pA * ra.x + pB * rb.x;
      acc.y += pA * ra.y + pB * rb.y;
      acc.z += pA * ra.z + pB * rb.z;
      acc.w += pA * ra.w + pB * rb.w;
      pa = qa; pb = qb; ra = nra; rb = nrb; qa = ta; qb = tb;
    }
    // combine the two edge streams
    ssum += __shfl_xor(ssum, 32, 64);
    acc.x += __shfl_xor(acc.x, 32, 64);
    acc.y += __shfl_xor(acc.y, 32, 64);
    acc.z += __shfl_xor(acc.z, 32, 64);
    acc.w += __shfl_xor(acc.w, 32, 64);
    float inv = 1.0f / (ssum + 1e-16f);
    float4 o = {acc.x * inv, acc.y * inv, acc.z * inv, acc.w * inv};
    // head mean: partner cl^16 holds the other head's same channel slot
    float px = __shfl_xor(o.x, 16, 64);
    float py = __shfl_xor(o.y, 16, 64);
    float pz = __shfl_xor(o.z, 16, 64);
    float pw = __shfl_xor(o.w, 16, 64);
    if (lane < 16) {
      float4 bv = bias[lane];
      float4 val = {0.5f * (o.x + px) + bv.x, 0.5f * (o.y + py) + bv.y,
                    0.5f * (o.z + pz) + bv.z, 0.5f * (o.w + pw) + bv.w};
      hout[(size_t)v * 16 + lane] = val;
      rs.x += val.x; rs.y += val.y; rs.z += val.z; rs.w += val.w;
      rq.x += val.x * val.x; rq.y += val.y * val.y;
      rq.z += val.z * val.z; rq.w += val.w * val.w;
    }
  }
  if (lane < 16) {
    lsum[wid][4 * lane] = rs.x; lsum[wid][4 * lane + 1] = rs.y;
    lsum[wid][4 * lane + 2] = rs.z; lsum[wid][4 * lane + 3] = rs.w;
    lsq[wid][4 * lane] = rq.x; lsq[wid][4 * lane + 1] = rq.y;
    lsq[wid][4 * lane + 2] = rq.z; lsq[wid][4 * lane + 3] = rq.w;
  }
  __syncthreads();
  if (threadIdx.x < 64) {
    float a = lsum[0][threadIdx.x] + lsum[1][threadIdx.x] + lsum[2][threadIdx.x] +
              lsum[3][threadIdx.x];
    float q = lsq[0][threadIdx.x] + lsq[1][threadIdx.x] + lsq[2][threadIdx.x] +
              lsq[3][threadIdx.x];
    atomicAdd(&bnsum[threadIdx.x], a);
    atomicAdd(&bnss[threadIdx.x], q);
  }
}

// HC=64: float2/lane; head0 = cl 0..15 (ch 2cl..2cl+1), head1 = cl 16..31.
__global__ void k_gat64(const int* __restrict__ off, const float4* __restrict__ ces,
                        const float2* __restrict__ xl, const float2* __restrict__ xr,
                        const float2* __restrict__ we, const float2* __restrict__ att,
                        const float2* __restrict__ bias, float2* __restrict__ hout,
                        float* __restrict__ bnsum, float* __restrict__ bnss) {
  __shared__ float lsum[4][32], lsq[4][32];
  int lane = threadIdx.x & 63;
  int wid = threadIdx.x >> 6;
  int cl = lane & 31;
  int half = lane >> 5;
  const float2 w0 = we[cl], w1 = we[32 + cl], w2 = we[64 + cl];
  const float2 av = att[cl];
  float2 rs = {0, 0}, rq = {0, 0};
  for (int v = blockIdx.x * 4 + wid; v < NN; v += gridDim.x * 4) {
    int b = off[v], e = off[v + 1];
    int last = e - 1;
    float2 xrv = xr[(size_t)v * 32 + cl];
    float ssum = 0.0f;
    float2 acc = {0, 0};
    int ng = (e - b + 3) >> 2;
    int j = b;
    float4 pa = ces[min(j + half, last)];
    float4 pb = ces[min(j + 2 + half, last)];
    float2 ra = xl[(size_t)__float_as_int(pa.w) * 32 + cl];
    float2 rb = xl[(size_t)__float_as_int(pb.w) * 32 + cl];
    float4 qa = ces[min(j + 4 + half, last)];
    float4 qb = ces[min(j + 6 + half, last)];
    for (int g = 0; g < ng; g++, j += 4) {
      float2 nra = xl[(size_t)__float_as_int(qa.w) * 32 + cl];
      float2 nrb = xl[(size_t)__float_as_int(qb.w) * 32 + cl];
      float4 ta = ces[min(j + 8 + half, last)];
      float4 tb = ces[min(j + 10 + half, last)];
      float2 ma, mb;
      ma.x = ra.x + xrv.x + pa.x * w0.x + pa.y * w1.x + pa.z * w2.x;
      ma.y = ra.y + xrv.y + pa.x * w0.y + pa.y * w1.y + pa.z * w2.y;
      mb.x = rb.x + xrv.x + pb.x * w0.x + pb.y * w1.x + pb.z * w2.x;
      mb.y = rb.y + xrv.y + pb.x * w0.y + pb.y * w1.y + pb.z * w2.y;
      ma.x = fmaxf(ma.x, 0.2f * ma.x); ma.y = fmaxf(ma.y, 0.2f * ma.y);
      mb.x = fmaxf(mb.x, 0.2f * mb.x); mb.y = fmaxf(mb.y, 0.2f * mb.y);
      float la = ma.x * av.x + ma.y * av.y;
      float lb = mb.x * av.x + mb.y * av.y;
#pragma unroll
      for (int m = 1; m <= 8; m <<= 1) {
        la += __shfl_xor(la, m, 64);
        lb += __shfl_xor(lb, m, 64);
      }
      float pA = ((j + half) < e) ? __expf(la) : 0.0f;
      float pB = ((j + 2 + half) < e) ? __expf(lb) : 0.0f;
      ssum += pA + pB;
      acc.x += pA * ra.x + pB * rb.x;
      acc.y += pA * ra.y + pB * rb.y;
      pa = qa; pb = qb; ra = nra; rb = nrb; qa = ta; qb = tb;
    }
    ssum += __shfl_xor(ssum, 32, 64);
    acc.x += __shfl_xor(acc.x, 32, 64);
    acc.y += __shfl_xor(acc.y, 32, 64);
    float inv = 1.0f / (ssum + 1e-16f);
    float2 o = {acc.x * inv, acc.y * inv};
    float px = __shfl_xor(o.x, 16, 64);
    float py = __shfl_xor(o.y, 16, 64);
    if (lane < 16) {
      float2 bv = bias[lane];
      float2 val = {0.5f * (o.x + px) + bv.x, 0.5f * (o.y + py) + bv.y};
      hout[(size_t)v * 16 + lane] = val;
      rs.x += val.x; rs.y += val.y;
      rq.x += val.x * val.x; rq.y += val.y * val.y;
    }
  }
  if (lane < 16) {
    lsum[wid][2 * lane] = rs.x; lsum[wid][2 * lane + 1] = rs.y;
    lsq[wid][2 * lane] = rq.x; lsq[wid][2 * lane + 1] = rq.y;
  }
  __syncthreads();
  if (threadIdx.x < 32) {
    float a = lsum[0][threadIdx.x] + lsum[1][threadIdx.x] + lsum[2][threadIdx.x] +
              lsum[3][threadIdx.x];
    float q = lsq[0][threadIdx.x] + lsq[1][threadIdx.x] + lsq[2][threadIdx.x] +
              lsq[3][threadIdx.x];
    atomicAdd(&bnsum[threadIdx.x], a);
    atomicAdd(&bnss[threadIdx.x], q);
  }
}

// ---------------- pooling (fused BN2+ELU) + head ----------------
// batch is sorted: graph offsets via binary search, no atomics.
__global__ void k_goffbs(const int* __restrict__ batch, int* __restrict__ goff) {
  int g = threadIdx.x;  // 512 threads
  int lo = 0, hi = NN;
  while (lo < hi) {
    int mid = (lo + hi) >> 1;
    if (batch[mid] < g) lo = mid + 1; else hi = mid;
  }
  goff[g] = lo;
  if (g == 0) goff[GG] = NN;
}

__global__ void k_pool(const float* __restrict__ h2, const int* __restrict__ goff,
                       const float* __restrict__ bnsum, const float* __restrict__ bnss,
                       const float* __restrict__ g, const float* __restrict__ be,
                       float* __restrict__ pooled) {
  int gi = blockIdx.x, c = threadIdx.x;  // 64 threads
  float mu = bnsum[c] * (1.0f / NN);
  float var = bnss[c] * (1.0f / NN) - mu * mu;
  float is = rsqrtf(var + BN_EPS) * g[c];
  float sh = be[c] - mu * is;
  int s = goff[gi], n = goff[gi + 1] - s;
  float acc = 0.0f;
  int i = 0;
  for (; i + 4 <= n; i += 4) {  // 4 independent loads in flight
    float y0 = h2[(size_t)(s + i) * 64 + c];
    float y1 = h2[(size_t)(s + i + 1) * 64 + c];
    float y2 = h2[(size_t)(s + i + 2) * 64 + c];
    float y3 = h2[(size_t)(s + i + 3) * 64 + c];
    y0 = y0 * is + sh; y1 = y1 * is + sh; y2 = y2 * is + sh; y3 = y3 * is + sh;
    y0 = (y0 > 0.0f) ? y0 : (__expf(y0) - 1.0f);
    y1 = (y1 > 0.0f) ? y1 : (__expf(y1) - 1.0f);
    y2 = (y2 > 0.0f) ? y2 : (__expf(y2) - 1.0f);
    y3 = (y3 > 0.0f) ? y3 : (__expf(y3) - 1.0f);
    acc += (y0 + y1) + (y2 + y3);
  }
  for (; i < n; i++) {
    float y = h2[(size_t)(s + i) * 64 + c] * is + sh;
    y = (y > 0.0f) ? y : (__expf(y) - 1.0f);
    acc += y;
  }
  pooled[gi * 64 + c] = acc / fmaxf((float)n, 1.0f);
}

__global__ void k_fc1(const float* __restrict__ pooled, const float* __restrict__ w,
                      const float* __restrict__ b, float* __restrict__ t1) {
  int i = blockIdx.x * blockDim.x + threadIdx.x;  // 16384
  int g = i >> 5, o = i & 31;
  float acc = b[o];
#pragma unroll 8
  for (int k = 0; k < 64; k++) acc += pooled[g * 64 + k] * w[k * 32 + o];
  t1[i] = acc;
}

__global__ void k_head(const float* __restrict__ t1, const float* __restrict__ g3,
                       const float* __restrict__ be3, const float* __restrict__ fc2w,
                       const float* __restrict__ fc2b, float* __restrict__ out) {
  __shared__ float ssum[32], ssq[32], smu[32], sinv[32];
  int t = threadIdx.x;  // 512 threads, one per graph
  if (t < 32) {
    ssum[t] = 0.0f;
    ssq[t] = 0.0f;
  }
  __syncthreads();
  float y[32];
#pragma unroll
  for (int o = 0; o < 32; o++) y[o] = t1[t * 32 + o];
#pragma unroll
  for (int o = 0; o < 32; o++) {
    atomicAdd(&ssum[o], y[o]);
    atomicAdd(&ssq[o], y[o] * y[o]);
  }
  __syncthreads();
  if (t < 32) {
    float mu = ssum[t] * (1.0f / GG);
    float var = ssq[t] * (1.0f / GG) - mu * mu;
    smu[t] = mu;
    sinv[t] = rsqrtf(var + BN_EPS);
  }
  __syncthreads();
  float acc = fc2b[0];
#pragma unroll
  for (int o = 0; o < 32; o++) {
    float yy = (y[o] - smu[o]) * sinv[o] * g3[o] + be3[o];
    yy = (yy > 0.0f) ? yy : (__expf(yy) - 1.0f);
    acc += yy * fc2w[o];
  }
  out[t] = 1.0f / (1.0f + __expf(-acc));
}

// ---------------- launch ----------------
extern "C" void kernel_launch(void* const* d_in, const int* in_sizes, int n_in,
                              void* d_out, int out_size, void* d_ws, size_t ws_size,
                              hipStream_t stream) {
  const float* x = (const float*)d_in[0];
  const float* ea = (const float*)d_in[1];
  const float* w1l = (const float*)d_in[2];
  const float* b1l = (const float*)d_in[3];
  const float* w1r = (const float*)d_in[4];
  const float* b1r = (const float*)d_in[5];
  const float* w1e = (const float*)d_in[6];
  const float* att1 = (const float*)d_in[7];
  const float* bias1 = (const float*)d_in[8];
  const float* g1 = (const float*)d_in[9];
  const float* be1 = (const float*)d_in[10];
  const float* w2l = (const float*)d_in[11];
  const float* b2l = (const float*)d_in[12];
  const float* w2r = (const float*)d_in[13];
  const float* b2r = (const float*)d_in[14];
  const float* w2e = (const float*)d_in[15];
  const float* att2 = (const float*)d_in[16];
  const float* bias2 = (const float*)d_in[17];
  const float* g2 = (const float*)d_in[18];
  const float* be2 = (const float*)d_in[19];
  const float* fc1w = (const float*)d_in[20];
  const float* fc1b = (const float*)d_in[21];
  const float* g3 = (const float*)d_in[22];
  const float* be3 = (const float*)d_in[23];
  const float* fc2w = (const float*)d_in[24];
  const float* fc2b = (const float*)d_in[25];
  const int* ei = (const int*)d_in[26];
  const int* batch = (const int*)d_in[27];
  float* out = (float*)d_out;

  char* w = (char*)d_ws;
  size_t off = 0;
  auto alloc = [&](size_t bytes) {
    size_t r = off;
    off += (bytes + 255) & ~(size_t)255;
    return r;
  };
  // zero-init region (one memset)
  int* cnt = (int*)(w + alloc(NN * 4));
  float* bn1sum = (float*)(w + alloc(32 * 4));
  float* bn1ss = (float*)(w + alloc(32 * 4));
  float* bn2sum = (float*)(w + alloc(64 * 4));
  float* bn2ss = (float*)(w + alloc(64 * 4));
  size_t zero_bytes = off;
  // rest
  int* rank = (int*)(w + alloc((size_t)EE * 4));
  int* csr_off = (int*)(w + alloc((size_t)(NN + 1) * 4));
  int* bsum = (int*)(w + alloc(512 * 4));
  int* goff = (int*)(w + alloc((size_t)(GG + 1) * 4));
  float4* ces = (float4*)(w + alloc((size_t)ET * 16));
  float* xl = (float*)(w + alloc((size_t)NN * 128 * 4));
  float* xr = (float*)(w + alloc((size_t)NN * 128 * 4));
  float* h1 = (float*)(w + alloc((size_t)NN * 32 * 4));
  float* h2 = (float*)(w + alloc((size_t)NN * 64 * 4));
  float* pooled = (float*)(w + alloc((size_t)GG * 64 * 4));
  float* t1 = (float*)(w + alloc((size_t)GG * 32 * 4));
  (void)ws_size;
  (void)in_sizes;
  (void)n_in;
  (void)out_size;

  hipMemsetAsync(d_ws, 0, zero_bytes, stream);

  // CSR build
  k_hist<<<EE / 256, 256, 0, stream>>>(ei, cnt, rank);
  k_scan_a<<<512, 256, 0, stream>>>(cnt, csr_off, bsum);
  k_scan_b<<<1, 512, 0, stream>>>(bsum);
  k_scan_c<<<512, 256, 0, stream>>>(csr_off, bsum);
  k_scatter<<<EE / 256, 256, 0, stream>>>(ei, ea, csr_off, rank, ces);
  k_selfslot<<<NN / 16, 256, 0, stream>>>(csr_off, ces);

  // layer 1 (HC=64, C=32)
  k_lin<64, 64, false><<<2048, 256, 0, stream>>>(x, w1l, b1l, w1r, b1r, xl, xr,
                                                 nullptr, nullptr, nullptr, nullptr);
  k_gat64<<<2048, 256, 0, stream>>>(csr_off, ces, (const float2*)xl,
                                    (const float2*)xr, (const float2*)w1e,
                                    (const float2*)att1, (const float2*)bias1,
                                    (float2*)h1, bn1sum, bn1ss);

  // layer 2 (HC=128, C=64) — BN1+ELU fused into the staging load
  k_lin<32, 128, true><<<2048, 256, 0, stream>>>(h1, w2l, b2l, w2r, b2r, xl, xr,
                                                 bn1sum, bn1ss, g1, be1);
  k_gat128<<<2048, 256, 0, stream>>>(csr_off, ces, (const float4*)xl,
                                     (const float4*)xr, (const float4*)w2e,
                                     (const float4*)att2, (const float4*)bias2,
                                     (float4*)h2, bn2sum, bn2ss);

  // pooling (BN2+ELU fused) + head
  k_goffbs<<<1, GG, 0, stream>>>(batch, goff);
  k_pool<<<GG, 64, 0, stream>>>(h2, goff, bn2sum, bn2ss, g2, be2, pooled);
  k_fc1<<<64, 256, 0, stream>>>(pooled, fc1w, fc1b, t1);
  k_head<<<1, GG, 0, stream>>>(t1, g3, be3, fc2w, fc2b, out);
}

// Round 8
// 990.175 us; speedup vs baseline: 1.4550x; 1.0208x over previous
//
#include <hip/hip_runtime.h>
#include <math.h>

#define NN 131072
#define EE 2097152
#define ET (EE + NN)
#define GG 512
#define BN_EPS 1e-5f

// bf16 helpers: xl is stored as bf16 (RNE) to halve the edge-gather stream.
__device__ __forceinline__ unsigned short f2bf(float f) {
  unsigned u = __float_as_uint(f);
  u += 0x7fffu + ((u >> 16) & 1u);  // round-nearest-even
  return (unsigned short)(u >> 16);
}
__device__ __forceinline__ float bf_lo(unsigned u) {  // low ushort -> float
  return __uint_as_float(u << 16);
}
__device__ __forceinline__ float bf_hi(unsigned u) {  // high ushort -> float
  return __uint_as_float(u & 0xffff0000u);
}

// ---------------- CSR build ----------------
// hist: in-degree count; atomic return value = within-node rank (reused by scatter)
__global__ void k_hist(const int* __restrict__ ei, int* __restrict__ cnt,
                       int* __restrict__ rank) {
  int e = blockIdx.x * blockDim.x + threadIdx.x;
  if (e >= EE) return;
  rank[e] = atomicAdd(&cnt[ei[EE + e]], 1);
}

__global__ void k_scan_a(const int* __restrict__ cnt, int* __restrict__ off_out,
                         int* __restrict__ bsum) {
  __shared__ int s[256];
  int i = blockIdx.x * 256 + threadIdx.x;
  int x = cnt[i] + 1;  // +1 self loop
  s[threadIdx.x] = x;
  __syncthreads();
#pragma unroll
  for (int o = 1; o < 256; o <<= 1) {
    int t = (threadIdx.x >= o) ? s[threadIdx.x - o] : 0;
    __syncthreads();
    s[threadIdx.x] += t;
    __syncthreads();
  }
  off_out[i] = s[threadIdx.x] - x;  // exclusive within block
  if (threadIdx.x == 255) bsum[blockIdx.x] = s[255];
}

__global__ void k_scan_b(int* __restrict__ bsum) {
  __shared__ int s[512];
  int t = threadIdx.x;
  int x = bsum[t];
  s[t] = x;
  __syncthreads();
#pragma unroll
  for (int o = 1; o < 512; o <<= 1) {
    int v = (t >= o) ? s[t - o] : 0;
    __syncthreads();
    s[t] += v;
    __syncthreads();
  }
  bsum[t] = s[t] - x;  // exclusive, in place
}

__global__ void k_scan_c(int* __restrict__ off_out, const int* __restrict__ bsum) {
  int i = blockIdx.x * 256 + threadIdx.x;
  off_out[i] += bsum[blockIdx.x];
  if (i == 0) off_out[NN] = ET;
}

// packed slot: {ea0, ea1, ea2, src-as-int-bits}; position from precomputed rank
__global__ void k_scatter(const int* __restrict__ ei, const float* __restrict__ ea,
                          const int* __restrict__ off, const int* __restrict__ rank,
                          float4* __restrict__ ces) {
  int e = blockIdx.x * blockDim.x + threadIdx.x;
  if (e >= EE) return;
  int s = ei[e], d = ei[EE + e];
  int p = off[d] + rank[e];
  float4 t = {ea[3 * e], ea[3 * e + 1], ea[3 * e + 2], __int_as_float(s)};
  ces[p] = t;
}

// self-loop slot = last slot of each node; attrs = mean of incoming real-edge
// attrs. Wave-cooperative: 4 nodes per wave, 16 lanes sweep each segment.
__global__ void k_selfslot(const int* __restrict__ off, float4* __restrict__ ces) {
  int tid = blockIdx.x * blockDim.x + threadIdx.x;
  int wave = tid >> 6;
  int lane = threadIdx.x & 63;
  int grp = lane >> 4;  // node sub-index within wave
  int gl = lane & 15;   // lane within 16-group
  int v = wave * 4 + grp;
  if (v >= NN) return;
  int b = off[v];
  int d = off[v + 1] - b - 1;  // real in-degree
  float s0 = 0.f, s1 = 0.f, s2 = 0.f;
  for (int j = gl; j < d; j += 16) {
    float4 t = ces[b + j];
    s0 += t.x;
    s1 += t.y;
    s2 += t.z;
  }
#pragma unroll
  for (int m = 1; m <= 8; m <<= 1) {  // reduce within 16-lane group
    s0 += __shfl_xor(s0, m, 64);
    s1 += __shfl_xor(s1, m, 64);
    s2 += __shfl_xor(s2, m, 64);
  }
  if (gl == 0) {
    float inv = 1.0f / (float)(d > 0 ? d : 1);
    float4 t = {s0 * inv, s1 * inv, s2 * inv, __int_as_float(v)};
    ces[b + d] = t;
  }
}

// ---------------- node linear: xl = f(x)@wl+bl (bf16) ; xr = f(x)@wr+br ------
template <int K, int O, bool DO_BN>
__global__ void k_lin(const float* __restrict__ x, const float* __restrict__ wl,
                      const float* __restrict__ bl, const float* __restrict__ wr,
                      const float* __restrict__ br, unsigned short* __restrict__ xlb,
                      float* __restrict__ xr, const float* __restrict__ bnsum,
                      const float* __restrict__ bnss, const float* __restrict__ g,
                      const float* __restrict__ be) {
  constexpr int NPB = 256 / O;  // nodes per block-iteration
  __shared__ float swl[K * O], swr[K * O], sx[NPB * K];
  __shared__ float sscale[K], sshift[K];
  for (int i = threadIdx.x; i < K * O; i += 256) {
    swl[i] = wl[i];
    swr[i] = wr[i];
  }
  if (DO_BN && threadIdx.x < K) {
    int c = threadIdx.x;
    float mu = bnsum[c] * (1.0f / NN);
    float var = bnss[c] * (1.0f / NN) - mu * mu;
    float is = rsqrtf(var + BN_EPS) * g[c];
    sscale[c] = is;
    sshift[c] = be[c] - mu * is;
  }
  int o = threadIdx.x % O;
  int ln = threadIdx.x / O;
  float blv = bl[o], brv = br[o];
  __syncthreads();
  for (int v0 = blockIdx.x * NPB; v0 < NN; v0 += gridDim.x * NPB) {
    __syncthreads();
    for (int i = threadIdx.x; i < NPB * K; i += 256) {
      float xv = x[(size_t)v0 * K + i];
      if (DO_BN) {
        int c = i & (K - 1);
        xv = xv * sscale[c] + sshift[c];
        xv = (xv > 0.0f) ? xv : (__expf(xv) - 1.0f);
      }
      sx[i] = xv;
    }
    __syncthreads();
    float al = blv, ar = brv;
#pragma unroll 8
    for (int k = 0; k < K; k++) {
      float xv = sx[ln * K + k];
      al += xv * swl[k * O + o];
      ar += xv * swr[k * O + o];
    }
    int v = v0 + ln;
    xlb[(size_t)v * O + o] = f2bf(al);
    xr[(size_t)v * O + o] = ar;
  }
}

// ---------------- fused GATv2 edge phase ----------------
// One wave per node. 32 channel-lanes (cl = lane&31) cover all HC channels;
// lane halves process 2 edge streams; 4 edges/iter, 2-stage pipeline.
// xl rows are bf16 (half the gather bytes); xr/ces/logits fp32.
// No running max (validated R2-R7).

// HC=128: 4 ch/lane; head0 = cl 0..15, head1 = cl 16..31.
__global__ void k_gat128(const int* __restrict__ off, const float4* __restrict__ ces,
                         const uint2* __restrict__ xlb, const float4* __restrict__ xr,
                         const float4* __restrict__ we, const float4* __restrict__ att,
                         const float4* __restrict__ bias, float4* __restrict__ hout,
                         float* __restrict__ bnsum, float* __restrict__ bnss) {
  __shared__ float lsum[4][64], lsq[4][64];
  int lane = threadIdx.x & 63;
  int wid = threadIdx.x >> 6;
  int cl = lane & 31;
  int half = lane >> 5;
  const float4 w0 = we[cl], w1 = we[32 + cl], w2 = we[64 + cl];
  const float4 av = att[cl];
  float4 rs = {0, 0, 0, 0}, rq = {0, 0, 0, 0};
  for (int v = blockIdx.x * 4 + wid; v < NN; v += gridDim.x * 4) {
    int b = off[v], e = off[v + 1];
    int last = e - 1;
    float4 xrv = xr[(size_t)v * 32 + cl];
    float ssum = 0.0f;
    float4 acc = {0, 0, 0, 0};
    int ng = (e - b + 3) >> 2;
    int j = b;
    float4 pa = ces[min(j + half, last)];
    float4 pb = ces[min(j + 2 + half, last)];
    uint2 ua = xlb[(size_t)__float_as_int(pa.w) * 32 + cl];
    uint2 ub = xlb[(size_t)__float_as_int(pb.w) * 32 + cl];
    float4 qa = ces[min(j + 4 + half, last)];
    float4 qb = ces[min(j + 6 + half, last)];
    for (int g = 0; g < ng; g++, j += 4) {
      uint2 nua = xlb[(size_t)__float_as_int(qa.w) * 32 + cl];
      uint2 nub = xlb[(size_t)__float_as_int(qb.w) * 32 + cl];
      float4 ta = ces[min(j + 8 + half, last)];
      float4 tb = ces[min(j + 10 + half, last)];
      float4 ra, rb;
      ra.x = bf_lo(ua.x); ra.y = bf_hi(ua.x); ra.z = bf_lo(ua.y); ra.w = bf_hi(ua.y);
      rb.x = bf_lo(ub.x); rb.y = bf_hi(ub.x); rb.z = bf_lo(ub.y); rb.w = bf_hi(ub.y);
      float4 ma, mb;
      ma.x = ra.x + xrv.x + pa.x * w0.x + pa.y * w1.x + pa.z * w2.x;
      ma.y = ra.y + xrv.y + pa.x * w0.y + pa.y * w1.y + pa.z * w2.y;
      ma.z = ra.z + xrv.z + pa.x * w0.z + pa.y * w1.z + pa.z * w2.z;
      ma.w = ra.w + xrv.w + pa.x * w0.w + pa.y * w1.w + pa.z * w2.w;
      mb.x = rb.x + xrv.x + pb.x * w0.x + pb.y * w1.x + pb.z * w2.x;
      mb.y = rb.y + xrv.y + pb.x * w0.y + pb.y * w1.y + pb.z * w2.y;
      mb.z = rb.z + xrv.z + pb.x * w0.z + pb.y * w1.z + pb.z * w2.z;
      mb.w = rb.w + xrv.w + pb.x * w0.w + pb.y * w1.w + pb.z * w2.w;
      ma.x = fmaxf(ma.x, 0.2f * ma.x); ma.y = fmaxf(ma.y, 0.2f * ma.y);
      ma.z = fmaxf(ma.z, 0.2f * ma.z); ma.w = fmaxf(ma.w, 0.2f * ma.w);
      mb.x = fmaxf(mb.x, 0.2f * mb.x); mb.y = fmaxf(mb.y, 0.2f * mb.y);
      mb.z = fmaxf(mb.z, 0.2f * mb.z); mb.w = fmaxf(mb.w, 0.2f * mb.w);
      float la = ma.x * av.x + ma.y * av.y + ma.z * av.z + ma.w * av.w;
      float lb = mb.x * av.x + mb.y * av.y + mb.z * av.z + mb.w * av.w;
#pragma unroll
      for (int m = 1; m <= 8; m <<= 1) {  // per-head reduce (16-lane groups)
        la += __shfl_xor(la, m, 64);
        lb += __shfl_xor(lb, m, 64);
      }
      float pA = ((j + half) < e) ? __expf(la) : 0.0f;
      float pB = ((j + 2 + half) < e) ? __expf(lb) : 0.0f;
      ssum += pA + pB;
      acc.x += pA * ra.x + pB * rb.x;
      acc.y += pA * ra.y + pB * rb.y;
      acc.z += pA * ra.z + pB * rb.z;
      acc.w += pA * ra.w + pB * rb.w;
      pa = qa; pb = qb; ua = nua; ub = nub; qa = ta; qb = tb;
    }
    // combine the two edge streams
    ssum += __shfl_xor(ssum, 32, 64);
    acc.x += __shfl_xor(acc.x, 32, 64);
    acc.y += __shfl_xor(acc.y, 32, 64);
    acc.z += __shfl_xor(acc.z, 32, 64);
    acc.w += __shfl_xor(acc.w, 32, 64);
    float inv = 1.0f / (ssum + 1e-16f);
    float4 o = {acc.x * inv, acc.y * inv, acc.z * inv, acc.w * inv};
    // head mean: partner cl^16 holds the other head's same channel slot
    float px = __shfl_xor(o.x, 16, 64);
    float py = __shfl_xor(o.y, 16, 64);
    float pz = __shfl_xor(o.z, 16, 64);
    float pw = __shfl_xor(o.w, 16, 64);
    if (lane < 16) {
      float4 bv = bias[lane];
      float4 val = {0.5f * (o.x + px) + bv.x, 0.5f * (o.y + py) + bv.y,
                    0.5f * (o.z + pz) + bv.z, 0.5f * (o.w + pw) + bv.w};
      hout[(size_t)v * 16 + lane] = val;
      rs.x += val.x; rs.y += val.y; rs.z += val.z; rs.w += val.w;
      rq.x += val.x * val.x; rq.y += val.y * val.y;
      rq.z += val.z * val.z; rq.w += val.w * val.w;
    }
  }
  if (lane < 16) {
    lsum[wid][4 * lane] = rs.x; lsum[wid][4 * lane + 1] = rs.y;
    lsum[wid][4 * lane + 2] = rs.z; lsum[wid][4 * lane + 3] = rs.w;
    lsq[wid][4 * lane] = rq.x; lsq[wid][4 * lane + 1] = rq.y;
    lsq[wid][4 * lane + 2] = rq.z; lsq[wid][4 * lane + 3] = rq.w;
  }
  __syncthreads();
  if (threadIdx.x < 64) {
    float a = lsum[0][threadIdx.x] + lsum[1][threadIdx.x] + lsum[2][threadIdx.x] +
              lsum[3][threadIdx.x];
    float q = lsq[0][threadIdx.x] + lsq[1][threadIdx.x] + lsq[2][threadIdx.x] +
              lsq[3][threadIdx.x];
    atomicAdd(&bnsum[threadIdx.x], a);
    atomicAdd(&bnss[threadIdx.x], q);
  }
}

// HC=64: 2 ch/lane; head0 = cl 0..15, head1 = cl 16..31.
__global__ void k_gat64(const int* __restrict__ off, const float4* __restrict__ ces,
                        const unsigned* __restrict__ xlb, const float2* __restrict__ xr,
                        const float2* __restrict__ we, const float2* __restrict__ att,
                        const float2* __restrict__ bias, float2* __restrict__ hout,
                        float* __restrict__ bnsum, float* __restrict__ bnss) {
  __shared__ float lsum[4][32], lsq[4][32];
  int lane = threadIdx.x & 63;
  int wid = threadIdx.x >> 6;
  int cl = lane & 31;
  int half = lane >> 5;
  const float2 w0 = we[cl], w1 = we[32 + cl], w2 = we[64 + cl];
  const float2 av = att[cl];
  float2 rs = {0, 0}, rq = {0, 0};
  for (int v = blockIdx.x * 4 + wid; v < NN; v += gridDim.x * 4) {
    int b = off[v], e = off[v + 1];
    int last = e - 1;
    float2 xrv = xr[(size_t)v * 32 + cl];
    float ssum = 0.0f;
    float2 acc = {0, 0};
    int ng = (e - b + 3) >> 2;
    int j = b;
    float4 pa = ces[min(j + half, last)];
    float4 pb = ces[min(j + 2 + half, last)];
    unsigned ua = xlb[(size_t)__float_as_int(pa.w) * 32 + cl];
    unsigned ub = xlb[(size_t)__float_as_int(pb.w) * 32 + cl];
    float4 qa = ces[min(j + 4 + half, last)];
    float4 qb = ces[min(j + 6 + half, last)];
    for (int g = 0; g < ng; g++, j += 4) {
      unsigned nua = xlb[(size_t)__float_as_int(qa.w) * 32 + cl];
      unsigned nub = xlb[(size_t)__float_as_int(qb.w) * 32 + cl];
      float4 ta = ces[min(j + 8 + half, last)];
      float4 tb = ces[min(j + 10 + half, last)];
      float2 ra = {bf_lo(ua), bf_hi(ua)};
      float2 rb = {bf_lo(ub), bf_hi(ub)};
      float2 ma, mb;
      ma.x = ra.x + xrv.x + pa.x * w0.x + pa.y * w1.x + pa.z * w2.x;
      ma.y = ra.y + xrv.y + pa.x * w0.y + pa.y * w1.y + pa.z * w2.y;
      mb.x = rb.x + xrv.x + pb.x * w0.x + pb.y * w1.x + pb.z * w2.x;
      mb.y = rb.y + xrv.y + pb.x * w0.y + pb.y * w1.y + pb.z * w2.y;
      ma.x = fmaxf(ma.x, 0.2f * ma.x); ma.y = fmaxf(ma.y, 0.2f * ma.y);
      mb.x = fmaxf(mb.x, 0.2f * mb.x); mb.y = fmaxf(mb.y, 0.2f * mb.y);
      float la = ma.x * av.x + ma.y * av.y;
      float lb = mb.x * av.x + mb.y * av.y;
#pragma unroll
      for (int m = 1; m <= 8; m <<= 1) {
        la += __shfl_xor(la, m, 64);
        lb += __shfl_xor(lb, m, 64);
      }
      float pA = ((j + half) < e) ? __expf(la) : 0.0f;
      float pB = ((j + 2 + half) < e) ? __expf(lb) : 0.0f;
      ssum += pA + pB;
      acc.x += pA * ra.x + pB * rb.x;
      acc.y += pA * ra.y + pB * rb.y;
      pa = qa; pb = qb; ua = nua; ub = nub; qa = ta; qb = tb;
    }
    ssum += __shfl_xor(ssum, 32, 64);
    acc.x += __shfl_xor(acc.x, 32, 64);
    acc.y += __shfl_xor(acc.y, 32, 64);
    float inv = 1.0f / (ssum + 1e-16f);
    float2 o = {acc.x * inv, acc.y * inv};
    float px = __shfl_xor(o.x, 16, 64);
    float py = __shfl_xor(o.y, 16, 64);
    if (lane < 16) {
      float2 bv = bias[lane];
      float2 val = {0.5f * (o.x + px) + bv.x, 0.5f * (o.y + py) + bv.y};
      hout[(size_t)v * 16 + lane] = val;
      rs.x += val.x; rs.y += val.y;
      rq.x += val.x * val.x; rq.y += val.y * val.y;
    }
  }
  if (lane < 16) {
    lsum[wid][2 * lane] = rs.x; lsum[wid][2 * lane + 1] = rs.y;
    lsq[wid][2 * lane] = rq.x; lsq[wid][2 * lane + 1] = rq.y;
  }
  __syncthreads();
  if (threadIdx.x < 32) {
    float a = lsum[0][threadIdx.x] + lsum[1][threadIdx.x] + lsum[2][threadIdx.x] +
              lsum[3][threadIdx.x];
    float q = lsq[0][threadIdx.x] + lsq[1][threadIdx.x] + lsq[2][threadIdx.x] +
              lsq[3][threadIdx.x];
    atomicAdd(&bnsum[threadIdx.x], a);
    atomicAdd(&bnss[threadIdx.x], q);
  }
}

// ---------------- pooling (fused BN2+ELU) + head ----------------
// batch is sorted: graph offsets via binary search, no atomics.
__global__ void k_goffbs(const int* __restrict__ batch, int* __restrict__ goff) {
  int g = threadIdx.x;  // 512 threads
  int lo = 0, hi = NN;
  while (lo < hi) {
    int mid = (lo + hi) >> 1;
    if (batch[mid] < g) lo = mid + 1; else hi = mid;
  }
  goff[g] = lo;
  if (g == 0) goff[GG] = NN;
}

__global__ void k_pool(const float* __restrict__ h2, const int* __restrict__ goff,
                       const float* __restrict__ bnsum, const float* __restrict__ bnss,
                       const float* __restrict__ g, const float* __restrict__ be,
                       float* __restrict__ pooled) {
  int gi = blockIdx.x, c = threadIdx.x;  // 64 threads
  float mu = bnsum[c] * (1.0f / NN);
  float var = bnss[c] * (1.0f / NN) - mu * mu;
  float is = rsqrtf(var + BN_EPS) * g[c];
  float sh = be[c] - mu * is;
  int s = goff[gi], n = goff[gi + 1] - s;
  float acc = 0.0f;
  int i = 0;
  for (; i + 4 <= n; i += 4) {  // 4 independent loads in flight
    float y0 = h2[(size_t)(s + i) * 64 + c];
    float y1 = h2[(size_t)(s + i + 1) * 64 + c];
    float y2 = h2[(size_t)(s + i + 2) * 64 + c];
    float y3 = h2[(size_t)(s + i + 3) * 64 + c];
    y0 = y0 * is + sh; y1 = y1 * is + sh; y2 = y2 * is + sh; y3 = y3 * is + sh;
    y0 = (y0 > 0.0f) ? y0 : (__expf(y0) - 1.0f);
    y1 = (y1 > 0.0f) ? y1 : (__expf(y1) - 1.0f);
    y2 = (y2 > 0.0f) ? y2 : (__expf(y2) - 1.0f);
    y3 = (y3 > 0.0f) ? y3 : (__expf(y3) - 1.0f);
    acc += (y0 + y1) + (y2 + y3);
  }
  for (; i < n; i++) {
    float y = h2[(size_t)(s + i) * 64 + c] * is + sh;
    y = (y > 0.0f) ? y : (__expf(y) - 1.0f);
    acc += y;
  }
  pooled[gi * 64 + c] = acc / fmaxf((float)n, 1.0f);
}

__global__ void k_fc1(const float* __restrict__ pooled, const float* __restrict__ w,
                      const float* __restrict__ b, float* __restrict__ t1) {
  int i = blockIdx.x * blockDim.x + threadIdx.x;  // 16384
  int g = i >> 5, o = i & 31;
  float acc = b[o];
#pragma unroll 8
  for (int k = 0; k < 64; k++) acc += pooled[g * 64 + k] * w[k * 32 + o];
  t1[i] = acc;
}

__global__ void k_head(const float* __restrict__ t1, const float* __restrict__ g3,
                       const float* __restrict__ be3, const float* __restrict__ fc2w,
                       const float* __restrict__ fc2b, float* __restrict__ out) {
  __shared__ float ssum[32], ssq[32], smu[32], sinv[32];
  int t = threadIdx.x;  // 512 threads, one per graph
  if (t < 32) {
    ssum[t] = 0.0f;
    ssq[t] = 0.0f;
  }
  __syncthreads();
  float y[32];
#pragma unroll
  for (int o = 0; o < 32; o++) y[o] = t1[t * 32 + o];
#pragma unroll
  for (int o = 0; o < 32; o++) {
    atomicAdd(&ssum[o], y[o]);
    atomicAdd(&ssq[o], y[o] * y[o]);
  }
  __syncthreads();
  if (t < 32) {
    float mu = ssum[t] * (1.0f / GG);
    float var = ssq[t] * (1.0f / GG) - mu * mu;
    smu[t] = mu;
    sinv[t] = rsqrtf(var + BN_EPS);
  }
  __syncthreads();
  float acc = fc2b[0];
#pragma unroll
  for (int o = 0; o < 32; o++) {
    float yy = (y[o] - smu[o]) * sinv[o] * g3[o] + be3[o];
    yy = (yy > 0.0f) ? yy : (__expf(yy) - 1.0f);
    acc += yy * fc2w[o];
  }
  out[t] = 1.0f / (1.0f + __expf(-acc));
}

// ---------------- launch ----------------
extern "C" void kernel_launch(void* const* d_in, const int* in_sizes, int n_in,
                              void* d_out, int out_size, void* d_ws, size_t ws_size,
                              hipStream_t stream) {
  const float* x = (const float*)d_in[0];
  const float* ea = (const float*)d_in[1];
  const float* w1l = (const float*)d_in[2];
  const float* b1l = (const float*)d_in[3];
  const float* w1r = (const float*)d_in[4];
  const float* b1r = (const float*)d_in[5];
  const float* w1e = (const float*)d_in[6];
  const float* att1 = (const float*)d_in[7];
  const float* bias1 = (const float*)d_in[8];
  const float* g1 = (const float*)d_in[9];
  const float* be1 = (const float*)d_in[10];
  const float* w2l = (const float*)d_in[11];
  const float* b2l = (const float*)d_in[12];
  const float* w2r = (const float*)d_in[13];
  const float* b2r = (const float*)d_in[14];
  const float* w2e = (const float*)d_in[15];
  const float* att2 = (const float*)d_in[16];
  const float* bias2 = (const float*)d_in[17];
  const float* g2 = (const float*)d_in[18];
  const float* be2 = (const float*)d_in[19];
  const float* fc1w = (const float*)d_in[20];
  const float* fc1b = (const float*)d_in[21];
  const float* g3 = (const float*)d_in[22];
  const float* be3 = (const float*)d_in[23];
  const float* fc2w = (const float*)d_in[24];
  const float* fc2b = (const float*)d_in[25];
  const int* ei = (const int*)d_in[26];
  const int* batch = (const int*)d_in[27];
  float* out = (float*)d_out;

  char* w = (char*)d_ws;
  size_t off = 0;
  auto alloc = [&](size_t bytes) {
    size_t r = off;
    off += (bytes + 255) & ~(size_t)255;
    return r;
  };
  // zero-init region (one memset)
  int* cnt = (int*)(w + alloc(NN * 4));
  float* bn1sum = (float*)(w + alloc(32 * 4));
  float* bn1ss = (float*)(w + alloc(32 * 4));
  float* bn2sum = (float*)(w + alloc(64 * 4));
  float* bn2ss = (float*)(w + alloc(64 * 4));
  size_t zero_bytes = off;
  // rest
  int* rank = (int*)(w + alloc((size_t)EE * 4));
  int* csr_off = (int*)(w + alloc((size_t)(NN + 1) * 4));
  int* bsum = (int*)(w + alloc(512 * 4));
  int* goff = (int*)(w + alloc((size_t)(GG + 1) * 4));
  float4* ces = (float4*)(w + alloc((size_t)ET * 16));
  unsigned short* xlb = (unsigned short*)(w + alloc((size_t)NN * 128 * 2));
  float* xr = (float*)(w + alloc((size_t)NN * 128 * 4));
  float* h1 = (float*)(w + alloc((size_t)NN * 32 * 4));
  float* h2 = (float*)(w + alloc((size_t)NN * 64 * 4));
  float* pooled = (float*)(w + alloc((size_t)GG * 64 * 4));
  float* t1 = (float*)(w + alloc((size_t)GG * 32 * 4));
  (void)ws_size;
  (void)in_sizes;
  (void)n_in;
  (void)out_size;

  hipMemsetAsync(d_ws, 0, zero_bytes, stream);

  // CSR build
  k_hist<<<EE / 256, 256, 0, stream>>>(ei, cnt, rank);
  k_scan_a<<<512, 256, 0, stream>>>(cnt, csr_off, bsum);
  k_scan_b<<<1, 512, 0, stream>>>(bsum);
  k_scan_c<<<512, 256, 0, stream>>>(csr_off, bsum);
  k_scatter<<<EE / 256, 256, 0, stream>>>(ei, ea, csr_off, rank, ces);
  k_selfslot<<<NN / 16, 256, 0, stream>>>(csr_off, ces);

  // layer 1 (HC=64, C=32)
  k_lin<64, 64, false><<<2048, 256, 0, stream>>>(x, w1l, b1l, w1r, b1r, xlb, xr,
                                                 nullptr, nullptr, nullptr, nullptr);
  k_gat64<<<2048, 256, 0, stream>>>(csr_off, ces, (const unsigned*)xlb,
                                    (const float2*)xr, (const float2*)w1e,
                                    (const float2*)att1, (const float2*)bias1,
                                    (float2*)h1, bn1sum, bn1ss);

  // layer 2 (HC=128, C=64) — BN1+ELU fused into the staging load
  k_lin<32, 128, true><<<2048, 256, 0, stream>>>(h1, w2l, b2l, w2r, b2r, xlb, xr,
                                                 bn1sum, bn1ss, g1, be1);
  k_gat128<<<2048, 256, 0, stream>>>(csr_off, ces, (const uint2*)xlb,
                                     (const float4*)xr, (const float4*)w2e,
                                     (const float4*)att2, (const float4*)bias2,
                                     (float4*)h2, bn2sum, bn2ss);

  // pooling (BN2+ELU fused) + head
  k_goffbs<<<1, GG, 0, stream>>>(batch, goff);
  k_pool<<<GG, 64, 0, stream>>>(h2, goff, bn2sum, bn2ss, g2, be2, pooled);
  k_fc1<<<64, 256, 0, stream>>>(pooled, fc1w, fc1b, t1);
  k_head<<<1, GG, 0, stream>>>(t1, g3, be3, fc2w, fc2b, out);
}

// Round 9
// 952.367 us; speedup vs baseline: 1.5128x; 1.0397x over previous
//
#include <hip/hip_runtime.h>
#include <math.h>

#define NN 131072
#define EE 2097152
#define ET (EE + NN)
#define GG 512
#define BN_EPS 1e-5f

// bf16 helpers: xl is stored as bf16 (RNE) to halve the edge-gather stream.
__device__ __forceinline__ unsigned short f2bf(float f) {
  unsigned u = __float_as_uint(f);
  u += 0x7fffu + ((u >> 16) & 1u);  // round-nearest-even
  return (unsigned short)(u >> 16);
}
__device__ __forceinline__ float bf_lo(unsigned u) { return __uint_as_float(u << 16); }
__device__ __forceinline__ float bf_hi(unsigned u) { return __uint_as_float(u & 0xffff0000u); }

// ---------------- CSR build ----------------
__global__ void k_hist(const int* __restrict__ ei, int* __restrict__ cnt,
                       int* __restrict__ rank) {
  int e = blockIdx.x * blockDim.x + threadIdx.x;
  if (e >= EE) return;
  rank[e] = atomicAdd(&cnt[ei[EE + e]], 1);
}

__global__ void k_scan_a(const int* __restrict__ cnt, int* __restrict__ off_out,
                         int* __restrict__ bsum) {
  __shared__ int s[256];
  int i = blockIdx.x * 256 + threadIdx.x;
  int x = cnt[i] + 1;  // +1 self loop
  s[threadIdx.x] = x;
  __syncthreads();
#pragma unroll
  for (int o = 1; o < 256; o <<= 1) {
    int t = (threadIdx.x >= o) ? s[threadIdx.x - o] : 0;
    __syncthreads();
    s[threadIdx.x] += t;
    __syncthreads();
  }
  off_out[i] = s[threadIdx.x] - x;  // exclusive within block
  if (threadIdx.x == 255) bsum[blockIdx.x] = s[255];
}

__global__ void k_scan_b(int* __restrict__ bsum) {
  __shared__ int s[512];
  int t = threadIdx.x;
  int x = bsum[t];
  s[t] = x;
  __syncthreads();
#pragma unroll
  for (int o = 1; o < 512; o <<= 1) {
    int v = (t >= o) ? s[t - o] : 0;
    __syncthreads();
    s[t] += v;
    __syncthreads();
  }
  bsum[t] = s[t] - x;  // exclusive, in place
}

__global__ void k_scan_c(int* __restrict__ off_out, const int* __restrict__ bsum) {
  int i = blockIdx.x * 256 + threadIdx.x;
  off_out[i] += bsum[blockIdx.x];
  if (i == 0) off_out[NN] = ET;
}

// packed slot: {ea0, ea1, ea2, src-as-int-bits}; position from precomputed rank
__global__ void k_scatter(const int* __restrict__ ei, const float* __restrict__ ea,
                          const int* __restrict__ off, const int* __restrict__ rank,
                          float4* __restrict__ ces) {
  int e = blockIdx.x * blockDim.x + threadIdx.x;
  if (e >= EE) return;
  int s = ei[e], d = ei[EE + e];
  int p = off[d] + rank[e];
  float4 t = {ea[3 * e], ea[3 * e + 1], ea[3 * e + 2], __int_as_float(s)};
  ces[p] = t;
}

// self-loop slot = last slot of each node; attrs = mean of incoming real-edge
// attrs. Wave-cooperative: 4 nodes per wave, 16 lanes sweep each segment.
// Also writes the 16 safe pad slots at ces[ET..ET+16) (src=node 0, masked out
// in gat by the jj<e predicate) so gat kernels need no min-clamps.
__global__ void k_selfslot(const int* __restrict__ off, float4* __restrict__ ces) {
  int tid = blockIdx.x * blockDim.x + threadIdx.x;
  if (tid < 16) {
    float4 z = {0.0f, 0.0f, 0.0f, __int_as_float(0)};
    ces[ET + tid] = z;
  }
  int wave = tid >> 6;
  int lane = threadIdx.x & 63;
  int grp = lane >> 4;  // node sub-index within wave
  int gl = lane & 15;   // lane within 16-group
  int v = wave * 4 + grp;
  if (v >= NN) return;
  int b = off[v];
  int d = off[v + 1] - b - 1;  // real in-degree
  float s0 = 0.f, s1 = 0.f, s2 = 0.f;
  for (int j = gl; j < d; j += 16) {
    float4 t = ces[b + j];
    s0 += t.x;
    s1 += t.y;
    s2 += t.z;
  }
#pragma unroll
  for (int m = 1; m <= 8; m <<= 1) {  // reduce within 16-lane group
    s0 += __shfl_xor(s0, m, 64);
    s1 += __shfl_xor(s1, m, 64);
    s2 += __shfl_xor(s2, m, 64);
  }
  if (gl == 0) {
    float inv = 1.0f / (float)(d > 0 ? d : 1);
    float4 t = {s0 * inv, s1 * inv, s2 * inv, __int_as_float(v)};
    ces[b + d] = t;
  }
}

// ---------------- node linear: xl = f(x)@wl+bl (bf16) ; xr = f(x)@wr+br ------
template <int K, int O, bool DO_BN>
__global__ void k_lin(const float* __restrict__ x, const float* __restrict__ wl,
                      const float* __restrict__ bl, const float* __restrict__ wr,
                      const float* __restrict__ br, unsigned short* __restrict__ xlb,
                      float* __restrict__ xr, const float* __restrict__ bnsum,
                      const float* __restrict__ bnss, const float* __restrict__ g,
                      const float* __restrict__ be) {
  constexpr int NPB = 256 / O;  // nodes per block-iteration
  __shared__ float swl[K * O], swr[K * O], sx[NPB * K];
  __shared__ float sscale[K], sshift[K];
  for (int i = threadIdx.x; i < K * O; i += 256) {
    swl[i] = wl[i];
    swr[i] = wr[i];
  }
  if (DO_BN && threadIdx.x < K) {
    int c = threadIdx.x;
    float mu = bnsum[c] * (1.0f / NN);
    float var = bnss[c] * (1.0f / NN) - mu * mu;
    float is = rsqrtf(var + BN_EPS) * g[c];
    sscale[c] = is;
    sshift[c] = be[c] - mu * is;
  }
  int o = threadIdx.x % O;
  int ln = threadIdx.x / O;
  float blv = bl[o], brv = br[o];
  __syncthreads();
  for (int v0 = blockIdx.x * NPB; v0 < NN; v0 += gridDim.x * NPB) {
    __syncthreads();
    for (int i = threadIdx.x; i < NPB * K; i += 256) {
      float xv = x[(size_t)v0 * K + i];
      if (DO_BN) {
        int c = i & (K - 1);
        xv = xv * sscale[c] + sshift[c];
        xv = (xv > 0.0f) ? xv : (__expf(xv) - 1.0f);
      }
      sx[i] = xv;
    }
    __syncthreads();
    float al = blv, ar = brv;
#pragma unroll 8
    for (int k = 0; k < K; k++) {
      float xv = sx[ln * K + k];
      al += xv * swl[k * O + o];
      ar += xv * swr[k * O + o];
    }
    int v = v0 + ln;
    xlb[(size_t)v * O + o] = f2bf(al);
    xr[(size_t)v * O + o] = ar;
  }
}

// ---------------- fused GATv2 edge phase ----------------
// One wave per node. 16 lanes per edge (el = lane&15), 4 edge streams per wave
// (st = lane>>4, stream s handles CSR slots b+s, b+s+4, ...). 2-stage pipeline:
// row for group g+1 and packed attr+src for group g+2 in flight. ces is padded
// (16 safe slots past ET) so no clamping is needed; invalid slots masked by the
// jj<e predicate. Per-head logit reduce: 3 shuffle steps within 8 lanes.
// No running max (validated R2-R8).

// HC=128: 8 ch/lane (uint4 bf16). head0 = el 0..7 (flat ch el*8..el*8+7).
__global__ void k_gat128(const int* __restrict__ off, const float4* __restrict__ ces,
                         const uint4* __restrict__ xlb, const float4* __restrict__ xr,
                         const float4* __restrict__ we, const float4* __restrict__ att,
                         const float4* __restrict__ bias, float4* __restrict__ hout,
                         float* __restrict__ bnsum, float* __restrict__ bnss) {
  __shared__ float lsum[4][64], lsq[4][64];
  int lane = threadIdx.x & 63;
  int wid = threadIdx.x >> 6;
  int el = lane & 15;  // channel group (8 ch)
  int st = lane >> 4;  // edge stream 0..3
  const float4 w0a = we[el * 2], w0b = we[el * 2 + 1];
  const float4 w1a = we[32 + el * 2], w1b = we[32 + el * 2 + 1];
  const float4 w2a = we[64 + el * 2], w2b = we[64 + el * 2 + 1];
  const float4 ava = att[el * 2], avb = att[el * 2 + 1];
  float4 rsa = {0, 0, 0, 0}, rsb = {0, 0, 0, 0};
  float4 rqa = {0, 0, 0, 0}, rqb = {0, 0, 0, 0};
  for (int v = blockIdx.x * 4 + wid; v < NN; v += gridDim.x * 4) {
    int b = off[v], e = off[v + 1];
    float4 xra = xr[(size_t)v * 32 + el * 2];
    float4 xrb = xr[(size_t)v * 32 + el * 2 + 1];
    float ssum = 0.0f;
    float4 acca = {0, 0, 0, 0}, accb = {0, 0, 0, 0};
    int ng = (e - b + 3) >> 2;
    int jj = b + st;
    float4 pa = ces[jj];
    uint4 ua = xlb[(size_t)__float_as_int(pa.w) * 16 + el];
    float4 qa = ces[jj + 4];
    for (int g = 0; g < ng; g++) {
      uint4 nua = xlb[(size_t)__float_as_int(qa.w) * 16 + el];
      float4 ta = ces[jj + 8];
      float4 ra, rb;
      ra.x = bf_lo(ua.x); ra.y = bf_hi(ua.x); ra.z = bf_lo(ua.y); ra.w = bf_hi(ua.y);
      rb.x = bf_lo(ua.z); rb.y = bf_hi(ua.z); rb.z = bf_lo(ua.w); rb.w = bf_hi(ua.w);
      float4 ma, mb;
      ma.x = ra.x + xra.x + pa.x * w0a.x + pa.y * w1a.x + pa.z * w2a.x;
      ma.y = ra.y + xra.y + pa.x * w0a.y + pa.y * w1a.y + pa.z * w2a.y;
      ma.z = ra.z + xra.z + pa.x * w0a.z + pa.y * w1a.z + pa.z * w2a.z;
      ma.w = ra.w + xra.w + pa.x * w0a.w + pa.y * w1a.w + pa.z * w2a.w;
      mb.x = rb.x + xrb.x + pa.x * w0b.x + pa.y * w1b.x + pa.z * w2b.x;
      mb.y = rb.y + xrb.y + pa.x * w0b.y + pa.y * w1b.y + pa.z * w2b.y;
      mb.z = rb.z + xrb.z + pa.x * w0b.z + pa.y * w1b.z + pa.z * w2b.z;
      mb.w = rb.w + xrb.w + pa.x * w0b.w + pa.y * w1b.w + pa.z * w2b.w;
      ma.x = fmaxf(ma.x, 0.2f * ma.x); ma.y = fmaxf(ma.y, 0.2f * ma.y);
      ma.z = fmaxf(ma.z, 0.2f * ma.z); ma.w = fmaxf(ma.w, 0.2f * ma.w);
      mb.x = fmaxf(mb.x, 0.2f * mb.x); mb.y = fmaxf(mb.y, 0.2f * mb.y);
      mb.z = fmaxf(mb.z, 0.2f * mb.z); mb.w = fmaxf(mb.w, 0.2f * mb.w);
      float l = ma.x * ava.x + ma.y * ava.y + ma.z * ava.z + ma.w * ava.w +
                mb.x * avb.x + mb.y * avb.y + mb.z * avb.z + mb.w * avb.w;
      l += __shfl_xor(l, 1, 64);
      l += __shfl_xor(l, 2, 64);
      l += __shfl_xor(l, 4, 64);  // per-head logit (8-lane groups)
      float p = (jj < e) ? __expf(l) : 0.0f;
      ssum += p;
      acca.x += p * ra.x; acca.y += p * ra.y; acca.z += p * ra.z; acca.w += p * ra.w;
      accb.x += p * rb.x; accb.y += p * rb.y; accb.z += p * rb.z; accb.w += p * rb.w;
      jj += 4;
      pa = qa; ua = nua; qa = ta;
    }
    // combine the 4 streams (masks 16, 32)
#pragma unroll
    for (int m = 16; m <= 32; m <<= 1) {
      ssum += __shfl_xor(ssum, m, 64);
      acca.x += __shfl_xor(acca.x, m, 64); acca.y += __shfl_xor(acca.y, m, 64);
      acca.z += __shfl_xor(acca.z, m, 64); acca.w += __shfl_xor(acca.w, m, 64);
      accb.x += __shfl_xor(accb.x, m, 64); accb.y += __shfl_xor(accb.y, m, 64);
      accb.z += __shfl_xor(accb.z, m, 64); accb.w += __shfl_xor(accb.w, m, 64);
    }
    float inv = 1.0f / (ssum + 1e-16f);
    float4 oa = {acca.x * inv, acca.y * inv, acca.z * inv, acca.w * inv};
    float4 ob = {accb.x * inv, accb.y * inv, accb.z * inv, accb.w * inv};
    // head mean: partner el^8 holds the other head's same channels
    float pax = __shfl_xor(oa.x, 8, 64), pay = __shfl_xor(oa.y, 8, 64);
    float paz = __shfl_xor(oa.z, 8, 64), paw = __shfl_xor(oa.w, 8, 64);
    float pbx = __shfl_xor(ob.x, 8, 64), pby = __shfl_xor(ob.y, 8, 64);
    float pbz = __shfl_xor(ob.z, 8, 64), pbw = __shfl_xor(ob.w, 8, 64);
    if (lane < 8) {  // st==0, el<8: channels el*8..el*8+7
      float4 bva = bias[el * 2], bvb = bias[el * 2 + 1];
      float4 va = {0.5f * (oa.x + pax) + bva.x, 0.5f * (oa.y + pay) + bva.y,
                   0.5f * (oa.z + paz) + bva.z, 0.5f * (oa.w + paw) + bva.w};
      float4 vb = {0.5f * (ob.x + pbx) + bvb.x, 0.5f * (ob.y + pby) + bvb.y,
                   0.5f * (ob.z + pbz) + bvb.z, 0.5f * (ob.w + pbw) + bvb.w};
      hout[(size_t)v * 16 + el * 2] = va;
      hout[(size_t)v * 16 + el * 2 + 1] = vb;
      rsa.x += va.x; rsa.y += va.y; rsa.z += va.z; rsa.w += va.w;
      rsb.x += vb.x; rsb.y += vb.y; rsb.z += vb.z; rsb.w += vb.w;
      rqa.x += va.x * va.x; rqa.y += va.y * va.y; rqa.z += va.z * va.z; rqa.w += va.w * va.w;
      rqb.x += vb.x * vb.x; rqb.y += vb.y * vb.y; rqb.z += vb.z * vb.z; rqb.w += vb.w * vb.w;
    }
  }
  if (lane < 8) {
    lsum[wid][el * 8 + 0] = rsa.x; lsum[wid][el * 8 + 1] = rsa.y;
    lsum[wid][el * 8 + 2] = rsa.z; lsum[wid][el * 8 + 3] = rsa.w;
    lsum[wid][el * 8 + 4] = rsb.x; lsum[wid][el * 8 + 5] = rsb.y;
    lsum[wid][el * 8 + 6] = rsb.z; lsum[wid][el * 8 + 7] = rsb.w;
    lsq[wid][el * 8 + 0] = rqa.x; lsq[wid][el * 8 + 1] = rqa.y;
    lsq[wid][el * 8 + 2] = rqa.z; lsq[wid][el * 8 + 3] = rqa.w;
    lsq[wid][el * 8 + 4] = rqb.x; lsq[wid][el * 8 + 5] = rqb.y;
    lsq[wid][el * 8 + 6] = rqb.z; lsq[wid][el * 8 + 7] = rqb.w;
  }
  __syncthreads();
  if (threadIdx.x < 64) {
    float a = lsum[0][threadIdx.x] + lsum[1][threadIdx.x] + lsum[2][threadIdx.x] +
              lsum[3][threadIdx.x];
    float q = lsq[0][threadIdx.x] + lsq[1][threadIdx.x] + lsq[2][threadIdx.x] +
              lsq[3][threadIdx.x];
    atomicAdd(&bnsum[threadIdx.x], a);
    atomicAdd(&bnss[threadIdx.x], q);
  }
}

// HC=64: 4 ch/lane (uint2 bf16). head0 = el 0..7 (flat ch el*4..el*4+3).
__global__ void k_gat64(const int* __restrict__ off, const float4* __restrict__ ces,
                        const uint2* __restrict__ xlb, const float4* __restrict__ xr,
                        const float4* __restrict__ we, const float4* __restrict__ att,
                        const float4* __restrict__ bias, float4* __restrict__ hout,
                        float* __restrict__ bnsum, float* __restrict__ bnss) {
  __shared__ float lsum[4][32], lsq[4][32];
  int lane = threadIdx.x & 63;
  int wid = threadIdx.x >> 6;
  int el = lane & 15;  // channel group (4 ch)
  int st = lane >> 4;  // edge stream 0..3
  const float4 w0 = we[el], w1 = we[16 + el], w2 = we[32 + el];
  const float4 av = att[el];
  float4 rs = {0, 0, 0, 0}, rq = {0, 0, 0, 0};
  for (int v = blockIdx.x * 4 + wid; v < NN; v += gridDim.x * 4) {
    int b = off[v], e = off[v + 1];
    float4 xrv = xr[(size_t)v * 16 + el];
    float ssum = 0.0f;
    float4 acc = {0, 0, 0, 0};
    int ng = (e - b + 3) >> 2;
    int jj = b + st;
    float4 pa = ces[jj];
    uint2 ua = xlb[(size_t)__float_as_int(pa.w) * 16 + el];
    float4 qa = ces[jj + 4];
    for (int g = 0; g < ng; g++) {
      uint2 nua = xlb[(size_t)__float_as_int(qa.w) * 16 + el];
      float4 ta = ces[jj + 8];
      float4 ra;
      ra.x = bf_lo(ua.x); ra.y = bf_hi(ua.x); ra.z = bf_lo(ua.y); ra.w = bf_hi(ua.y);
      float4 ma;
      ma.x = ra.x + xrv.x + pa.x * w0.x + pa.y * w1.x + pa.z * w2.x;
      ma.y = ra.y + xrv.y + pa.x * w0.y + pa.y * w1.y + pa.z * w2.y;
      ma.z = ra.z + xrv.z + pa.x * w0.z + pa.y * w1.z + pa.z * w2.z;
      ma.w = ra.w + xrv.w + pa.x * w0.w + pa.y * w1.w + pa.z * w2.w;
      ma.x = fmaxf(ma.x, 0.2f * ma.x); ma.y = fmaxf(ma.y, 0.2f * ma.y);
      ma.z = fmaxf(ma.z, 0.2f * ma.z); ma.w = fmaxf(ma.w, 0.2f * ma.w);
      float l = ma.x * av.x + ma.y * av.y + ma.z * av.z + ma.w * av.w;
      l += __shfl_xor(l, 1, 64);
      l += __shfl_xor(l, 2, 64);
      l += __shfl_xor(l, 4, 64);  // per-head logit (8-lane groups)
      float p = (jj < e) ? __expf(l) : 0.0f;
      ssum += p;
      acc.x += p * ra.x; acc.y += p * ra.y; acc.z += p * ra.z; acc.w += p * ra.w;
      jj += 4;
      pa = qa; ua = nua; qa = ta;
    }
#pragma unroll
    for (int m = 16; m <= 32; m <<= 1) {
      ssum += __shfl_xor(ssum, m, 64);
      acc.x += __shfl_xor(acc.x, m, 64); acc.y += __shfl_xor(acc.y, m, 64);
      acc.z += __shfl_xor(acc.z, m, 64); acc.w += __shfl_xor(acc.w, m, 64);
    }
    float inv = 1.0f / (ssum + 1e-16f);
    float4 o = {acc.x * inv, acc.y * inv, acc.z * inv, acc.w * inv};
    float px = __shfl_xor(o.x, 8, 64), py = __shfl_xor(o.y, 8, 64);
    float pz = __shfl_xor(o.z, 8, 64), pw = __shfl_xor(o.w, 8, 64);
    if (lane < 8) {  // st==0, el<8: channels el*4..el*4+3
      float4 bv = bias[el];
      float4 val = {0.5f * (o.x + px) + bv.x, 0.5f * (o.y + py) + bv.y,
                    0.5f * (o.z + pz) + bv.z, 0.5f * (o.w + pw) + bv.w};
      hout[(size_t)v * 8 + el] = val;
      rs.x += val.x; rs.y += val.y; rs.z += val.z; rs.w += val.w;
      rq.x += val.x * val.x; rq.y += val.y * val.y;
      rq.z += val.z * val.z; rq.w += val.w * val.w;
    }
  }
  if (lane < 8) {
    lsum[wid][el * 4 + 0] = rs.x; lsum[wid][el * 4 + 1] = rs.y;
    lsum[wid][el * 4 + 2] = rs.z; lsum[wid][el * 4 + 3] = rs.w;
    lsq[wid][el * 4 + 0] = rq.x; lsq[wid][el * 4 + 1] = rq.y;
    lsq[wid][el * 4 + 2] = rq.z; lsq[wid][el * 4 + 3] = rq.w;
  }
  __syncthreads();
  if (threadIdx.x < 32) {
    float a = lsum[0][threadIdx.x] + lsum[1][threadIdx.x] + lsum[2][threadIdx.x] +
              lsum[3][threadIdx.x];
    float q = lsq[0][threadIdx.x] + lsq[1][threadIdx.x] + lsq[2][threadIdx.x] +
              lsq[3][threadIdx.x];
    atomicAdd(&bnsum[threadIdx.x], a);
    atomicAdd(&bnss[threadIdx.x], q);
  }
}

// ---------------- pooling (fused BN2+ELU) + head ----------------
// batch is sorted: graph offsets via binary search, no atomics.
__global__ void k_goffbs(const int* __restrict__ batch, int* __restrict__ goff) {
  int g = threadIdx.x;  // 512 threads
  int lo = 0, hi = NN;
  while (lo < hi) {
    int mid = (lo + hi) >> 1;
    if (batch[mid] < g) lo = mid + 1; else hi = mid;
  }
  goff[g] = lo;
  if (g == 0) goff[GG] = NN;
}

__global__ void k_pool(const float* __restrict__ h2, const int* __restrict__ goff,
                       const float* __restrict__ bnsum, const float* __restrict__ bnss,
                       const float* __restrict__ g, const float* __restrict__ be,
                       float* __restrict__ pooled) {
  int gi = blockIdx.x, c = threadIdx.x;  // 64 threads
  float mu = bnsum[c] * (1.0f / NN);
  float var = bnss[c] * (1.0f / NN) - mu * mu;
  float is = rsqrtf(var + BN_EPS) * g[c];
  float sh = be[c] - mu * is;
  int s = goff[gi], n = goff[gi + 1] - s;
  float acc = 0.0f;
  int i = 0;
  for (; i + 4 <= n; i += 4) {  // 4 independent loads in flight
    float y0 = h2[(size_t)(s + i) * 64 + c];
    float y1 = h2[(size_t)(s + i + 1) * 64 + c];
    float y2 = h2[(size_t)(s + i + 2) * 64 + c];
    float y3 = h2[(size_t)(s + i + 3) * 64 + c];
    y0 = y0 * is + sh; y1 = y1 * is + sh; y2 = y2 * is + sh; y3 = y3 * is + sh;
    y0 = (y0 > 0.0f) ? y0 : (__expf(y0) - 1.0f);
    y1 = (y1 > 0.0f) ? y1 : (__expf(y1) - 1.0f);
    y2 = (y2 > 0.0f) ? y2 : (__expf(y2) - 1.0f);
    y3 = (y3 > 0.0f) ? y3 : (__expf(y3) - 1.0f);
    acc += (y0 + y1) + (y2 + y3);
  }
  for (; i < n; i++) {
    float y = h2[(size_t)(s + i) * 64 + c] * is + sh;
    y = (y > 0.0f) ? y : (__expf(y) - 1.0f);
    acc += y;
  }
  pooled[gi * 64 + c] = acc / fmaxf((float)n, 1.0f);
}

__global__ void k_fc1(const float* __restrict__ pooled, const float* __restrict__ w,
                      const float* __restrict__ b, float* __restrict__ t1) {
  int i = blockIdx.x * blockDim.x + threadIdx.x;  // 16384
  int g = i >> 5, o = i & 31;
  float acc = b[o];
#pragma unroll 8
  for (int k = 0; k < 64; k++) acc += pooled[g * 64 + k] * w[k * 32 + o];
  t1[i] = acc;
}

__global__ void k_head(const float* __restrict__ t1, const float* __restrict__ g3,
                       const float* __restrict__ be3, const float* __restrict__ fc2w,
                       const float* __restrict__ fc2b, float* __restrict__ out) {
  __shared__ float ssum[32], ssq[32], smu[32], sinv[32];
  int t = threadIdx.x;  // 512 threads, one per graph
  if (t < 32) {
    ssum[t] = 0.0f;
    ssq[t] = 0.0f;
  }
  __syncthreads();
  float y[32];
#pragma unroll
  for (int o = 0; o < 32; o++) y[o] = t1[t * 32 + o];
#pragma unroll
  for (int o = 0; o < 32; o++) {
    atomicAdd(&ssum[o], y[o]);
    atomicAdd(&ssq[o], y[o] * y[o]);
  }
  __syncthreads();
  if (t < 32) {
    float mu = ssum[t] * (1.0f / GG);
    float var = ssq[t] * (1.0f / GG) - mu * mu;
    smu[t] = mu;
    sinv[t] = rsqrtf(var + BN_EPS);
  }
  __syncthreads();
  float acc = fc2b[0];
#pragma unroll
  for (int o = 0; o < 32; o++) {
    float yy = (y[o] - smu[o]) * sinv[o] * g3[o] + be3[o];
    yy = (yy > 0.0f) ? yy : (__expf(yy) - 1.0f);
    acc += yy * fc2w[o];
  }
  out[t] = 1.0f / (1.0f + __expf(-acc));
}

// ---------------- launch ----------------
extern "C" void kernel_launch(void* const* d_in, const int* in_sizes, int n_in,
                              void* d_out, int out_size, void* d_ws, size_t ws_size,
                              hipStream_t stream) {
  const float* x = (const float*)d_in[0];
  const float* ea = (const float*)d_in[1];
  const float* w1l = (const float*)d_in[2];
  const float* b1l = (const float*)d_in[3];
  const float* w1r = (const float*)d_in[4];
  const float* b1r = (const float*)d_in[5];
  const float* w1e = (const float*)d_in[6];
  const float* att1 = (const float*)d_in[7];
  const float* bias1 = (const float*)d_in[8];
  const float* g1 = (const float*)d_in[9];
  const float* be1 = (const float*)d_in[10];
  const float* w2l = (const float*)d_in[11];
  const float* b2l = (const float*)d_in[12];
  const float* w2r = (const float*)d_in[13];
  const float* b2r = (const float*)d_in[14];
  const float* w2e = (const float*)d_in[15];
  const float* att2 = (const float*)d_in[16];
  const float* bias2 = (const float*)d_in[17];
  const float* g2 = (const float*)d_in[18];
  const float* be2 = (const float*)d_in[19];
  const float* fc1w = (const float*)d_in[20];
  const float* fc1b = (const float*)d_in[21];
  const float* g3 = (const float*)d_in[22];
  const float* be3 = (const float*)d_in[23];
  const float* fc2w = (const float*)d_in[24];
  const float* fc2b = (const float*)d_in[25];
  const int* ei = (const int*)d_in[26];
  const int* batch = (const int*)d_in[27];
  float* out = (float*)d_out;

  char* w = (char*)d_ws;
  size_t off = 0;
  auto alloc = [&](size_t bytes) {
    size_t r = off;
    off += (bytes + 255) & ~(size_t)255;
    return r;
  };
  // zero-init region (one memset)
  int* cnt = (int*)(w + alloc(NN * 4));
  float* bn1sum = (float*)(w + alloc(32 * 4));
  float* bn1ss = (float*)(w + alloc(32 * 4));
  float* bn2sum = (float*)(w + alloc(64 * 4));
  float* bn2ss = (float*)(w + alloc(64 * 4));
  size_t zero_bytes = off;
  // rest
  int* rank = (int*)(w + alloc((size_t)EE * 4));
  int* csr_off = (int*)(w + alloc((size_t)(NN + 1) * 4));
  int* bsum = (int*)(w + alloc(512 * 4));
  int* goff = (int*)(w + alloc((size_t)(GG + 1) * 4));
  float4* ces = (float4*)(w + alloc((size_t)(ET + 16) * 16));  // +16 pad slots
  unsigned short* xlb = (unsigned short*)(w + alloc((size_t)NN * 128 * 2));
  float* xr = (float*)(w + alloc((size_t)NN * 128 * 4));
  float* h1 = (float*)(w + alloc((size_t)NN * 32 * 4));
  float* h2 = (float*)(w + alloc((size_t)NN * 64 * 4));
  float* pooled = (float*)(w + alloc((size_t)GG * 64 * 4));
  float* t1 = (float*)(w + alloc((size_t)GG * 32 * 4));
  (void)ws_size;
  (void)in_sizes;
  (void)n_in;
  (void)out_size;

  hipMemsetAsync(d_ws, 0, zero_bytes, stream);

  // CSR build
  k_hist<<<EE / 256, 256, 0, stream>>>(ei, cnt, rank);
  k_scan_a<<<512, 256, 0, stream>>>(cnt, csr_off, bsum);
  k_scan_b<<<1, 512, 0, stream>>>(bsum);
  k_scan_c<<<512, 256, 0, stream>>>(csr_off, bsum);
  k_scatter<<<EE / 256, 256, 0, stream>>>(ei, ea, csr_off, rank, ces);
  k_selfslot<<<NN / 16, 256, 0, stream>>>(csr_off, ces);

  // layer 1 (HC=64, C=32)
  k_lin<64, 64, false><<<2048, 256, 0, stream>>>(x, w1l, b1l, w1r, b1r, xlb, xr,
                                                 nullptr, nullptr, nullptr, nullptr);
  k_gat64<<<2048, 256, 0, stream>>>(csr_off, ces, (const uint2*)xlb,
                                    (const float4*)xr, (const float4*)w1e,
                                    (const float4*)att1, (const float4*)bias1,
                                    (float4*)h1, bn1sum, bn1ss);

  // layer 2 (HC=128, C=64) — BN1+ELU fused into the staging load
  k_lin<32, 128, true><<<2048, 256, 0, stream>>>(h1, w2l, b2l, w2r, b2r, xlb, xr,
                                                 bn1sum, bn1ss, g1, be1);
  k_gat128<<<2048, 256, 0, stream>>>(csr_off, ces, (const uint4*)xlb,
                                     (const float4*)xr, (const float4*)w2e,
                                     (const float4*)att2, (const float4*)bias2,
                                     (float4*)h2, bn2sum, bn2ss);

  // pooling (BN2+ELU fused) + head
  k_goffbs<<<1, GG, 0, stream>>>(batch, goff);
  k_pool<<<GG, 64, 0, stream>>>(h2, goff, bn2sum, bn2ss, g2, be2, pooled);
  k_fc1<<<64, 256, 0, stream>>>(pooled, fc1w, fc1b, t1);
  k_head<<<1, GG, 0, stream>>>(t1, g3, be3, fc2w, fc2b, out);
}

// Round 10
// 862.647 us; speedup vs baseline: 1.6701x; 1.1040x over previous
//
#include <hip/hip_runtime.h>
#include <math.h>

#define NN 131072
#define EE 2097152
#define ET (EE + NN)
#define GG 512
#define BN_EPS 1e-5f

// bf16 helpers: xl is stored as bf16 (RNE) to halve the edge-gather stream.
__device__ __forceinline__ unsigned short f2bf(float f) {
  unsigned u = __float_as_uint(f);
  u += 0x7fffu + ((u >> 16) & 1u);  // round-nearest-even
  return (unsigned short)(u >> 16);
}
__device__ __forceinline__ float bf_lo(unsigned u) { return __uint_as_float(u << 16); }
__device__ __forceinline__ float bf_hi(unsigned u) { return __uint_as_float(u & 0xffff0000u); }

// ---------------- CSR build ----------------
__global__ void k_hist(const int* __restrict__ ei, int* __restrict__ cnt,
                       int* __restrict__ rank) {
  int e = blockIdx.x * blockDim.x + threadIdx.x;
  if (e >= EE) return;
  rank[e] = atomicAdd(&cnt[ei[EE + e]], 1);
}

__global__ void k_scan_a(const int* __restrict__ cnt, int* __restrict__ off_out,
                         int* __restrict__ bsum) {
  __shared__ int s[256];
  int i = blockIdx.x * 256 + threadIdx.x;
  int x = cnt[i] + 1;  // +1 self loop
  s[threadIdx.x] = x;
  __syncthreads();
#pragma unroll
  for (int o = 1; o < 256; o <<= 1) {
    int t = (threadIdx.x >= o) ? s[threadIdx.x - o] : 0;
    __syncthreads();
    s[threadIdx.x] += t;
    __syncthreads();
  }
  off_out[i] = s[threadIdx.x] - x;  // exclusive within block
  if (threadIdx.x == 255) bsum[blockIdx.x] = s[255];
}

__global__ void k_scan_b(int* __restrict__ bsum) {
  __shared__ int s[512];
  int t = threadIdx.x;
  int x = bsum[t];
  s[t] = x;
  __syncthreads();
#pragma unroll
  for (int o = 1; o < 512; o <<= 1) {
    int v = (t >= o) ? s[t - o] : 0;
    __syncthreads();
    s[t] += v;
    __syncthreads();
  }
  bsum[t] = s[t] - x;  // exclusive, in place
}

__global__ void k_scan_c(int* __restrict__ off_out, const int* __restrict__ bsum) {
  int i = blockIdx.x * 256 + threadIdx.x;
  off_out[i] += bsum[blockIdx.x];
  if (i == 0) off_out[NN] = ET;
}

// packed slot: {ea0, ea1, ea2, src-as-int-bits}; position from precomputed rank
__global__ void k_scatter(const int* __restrict__ ei, const float* __restrict__ ea,
                          const int* __restrict__ off, const int* __restrict__ rank,
                          float4* __restrict__ ces) {
  int e = blockIdx.x * blockDim.x + threadIdx.x;
  if (e >= EE) return;
  int s = ei[e], d = ei[EE + e];
  unsigned p = (unsigned)(off[d] + rank[e]);
  float4 t = {ea[3 * e], ea[3 * e + 1], ea[3 * e + 2], __int_as_float(s)};
  ces[p] = t;
}

// self-loop slot = last slot of each node; attrs = mean of incoming real-edge
// attrs. Wave-cooperative: 4 nodes per wave, 16 lanes sweep each segment.
// Also writes the 16 safe pad slots at ces[ET..ET+16).
__global__ void k_selfslot(const int* __restrict__ off, float4* __restrict__ ces) {
  int tid = blockIdx.x * blockDim.x + threadIdx.x;
  if (tid < 16) {
    float4 z = {0.0f, 0.0f, 0.0f, __int_as_float(0)};
    ces[ET + tid] = z;
  }
  int wave = tid >> 6;
  int lane = threadIdx.x & 63;
  int grp = lane >> 4;  // node sub-index within wave
  int gl = lane & 15;   // lane within 16-group
  int v = wave * 4 + grp;
  if (v >= NN) return;
  int b = off[v];
  int d = off[v + 1] - b - 1;  // real in-degree
  float s0 = 0.f, s1 = 0.f, s2 = 0.f;
  for (int j = gl; j < d; j += 16) {
    float4 t = ces[(unsigned)(b + j)];
    s0 += t.x;
    s1 += t.y;
    s2 += t.z;
  }
#pragma unroll
  for (int m = 1; m <= 8; m <<= 1) {  // reduce within 16-lane group
    s0 += __shfl_xor(s0, m, 64);
    s1 += __shfl_xor(s1, m, 64);
    s2 += __shfl_xor(s2, m, 64);
  }
  if (gl == 0) {
    float inv = 1.0f / (float)(d > 0 ? d : 1);
    float4 t = {s0 * inv, s1 * inv, s2 * inv, __int_as_float(v)};
    ces[(unsigned)(b + d)] = t;
  }
}

// ---------------- node linear: xl = f(x)@wl+bl (bf16) ; xr = f(x)@wr+br ------
// Register-tiled: transposed weights [o][K+4] in LDS, k-tiles of 16 held in
// 8 float4 regs, 4 nodes per thread so weight LDS bytes amortize 4x.
template <int K, int O, bool DO_BN>
__global__ void k_lin(const float* __restrict__ x, const float* __restrict__ wl,
                      const float* __restrict__ bl, const float* __restrict__ wr,
                      const float* __restrict__ br, unsigned short* __restrict__ xlb,
                      float* __restrict__ xr, const float* __restrict__ bnsum,
                      const float* __restrict__ bnss, const float* __restrict__ g,
                      const float* __restrict__ be) {
  constexpr int KP = K + 4;        // padded stride: 16B-aligned, bank-staggered
  constexpr int RG = 256 / O;      // row-groups per block
  constexpr int NPG = 4;           // nodes per row-group (per thread)
  constexpr int NPB = RG * NPG;    // nodes per block-iteration
  constexpr int NT = K / 16;       // k-tiles
  __shared__ float swl[O * KP], swr[O * KP], sx[NPB * K];
  __shared__ float sscale[K], sshift[K];
  for (int i = threadIdx.x; i < K * O; i += 256) {
    int k = i / O, o = i % O;
    swl[o * KP + k] = wl[i];
    swr[o * KP + k] = wr[i];
  }
  if (DO_BN && threadIdx.x < K) {
    int c = threadIdx.x;
    float mu = bnsum[c] * (1.0f / NN);
    float var = bnss[c] * (1.0f / NN) - mu * mu;
    float is = rsqrtf(var + BN_EPS) * g[c];
    sscale[c] = is;
    sshift[c] = be[c] - mu * is;
  }
  int o = threadIdx.x % O;
  int rg = threadIdx.x / O;
  float blv = bl[o], brv = br[o];
  __syncthreads();
  for (int v0 = blockIdx.x * NPB; v0 < NN; v0 += gridDim.x * NPB) {
    __syncthreads();
    for (int i = threadIdx.x; i < NPB * K; i += 256) {
      float xv = x[(size_t)v0 * K + i];
      if (DO_BN) {
        int c = i & (K - 1);
        xv = xv * sscale[c] + sshift[c];
        xv = (xv > 0.0f) ? xv : (__expf(xv) - 1.0f);
      }
      sx[i] = xv;
    }
    __syncthreads();
    float al[NPG], ar[NPG];
#pragma unroll
    for (int n = 0; n < NPG; n++) { al[n] = blv; ar[n] = brv; }
#pragma unroll
    for (int t = 0; t < NT; t++) {
      const float* wlp = &swl[o * KP + t * 16];
      const float* wrp = &swr[o * KP + t * 16];
      float4 L0 = *(const float4*)&wlp[0], L1 = *(const float4*)&wlp[4];
      float4 L2 = *(const float4*)&wlp[8], L3 = *(const float4*)&wlp[12];
      float4 R0 = *(const float4*)&wrp[0], R1 = *(const float4*)&wrp[4];
      float4 R2 = *(const float4*)&wrp[8], R3 = *(const float4*)&wrp[12];
#pragma unroll
      for (int n = 0; n < NPG; n++) {
        const float* sxp = &sx[(rg * NPG + n) * K + t * 16];
        float4 X0 = *(const float4*)&sxp[0], X1 = *(const float4*)&sxp[4];
        float4 X2 = *(const float4*)&sxp[8], X3 = *(const float4*)&sxp[12];
        al[n] += X0.x * L0.x + X0.y * L0.y + X0.z * L0.z + X0.w * L0.w +
                 X1.x * L1.x + X1.y * L1.y + X1.z * L1.z + X1.w * L1.w +
                 X2.x * L2.x + X2.y * L2.y + X2.z * L2.z + X2.w * L2.w +
                 X3.x * L3.x + X3.y * L3.y + X3.z * L3.z + X3.w * L3.w;
        ar[n] += X0.x * R0.x + X0.y * R0.y + X0.z * R0.z + X0.w * R0.w +
                 X1.x * R1.x + X1.y * R1.y + X1.z * R1.z + X1.w * R1.w +
                 X2.x * R2.x + X2.y * R2.y + X2.z * R2.z + X2.w * R2.w +
                 X3.x * R3.x + X3.y * R3.y + X3.z * R3.z + X3.w * R3.w;
      }
    }
#pragma unroll
    for (int n = 0; n < NPG; n++) {
      int v = v0 + rg * NPG + n;
      xlb[(size_t)v * O + o] = f2bf(al[n]);
      xr[(size_t)v * O + o] = ar[n];
    }
  }
}

// ---------------- fused GATv2 edge phase ----------------
// One wave per node. 16 lanes per edge (el = lane&15), 4 edge streams per wave.
// 2-stage pipeline; ces padded so no clamps; invalid slots masked by jj<e.
// 32-bit index math for all gathers (tables < 4 GB). No running max (R2-R9).

// HC=128: 8 ch/lane (uint4 bf16). head0 = el 0..7.
__global__ void k_gat128(const int* __restrict__ off, const float4* __restrict__ ces,
                         const uint4* __restrict__ xlb, const float4* __restrict__ xr,
                         const float4* __restrict__ we, const float4* __restrict__ att,
                         const float4* __restrict__ bias, float4* __restrict__ hout,
                         float* __restrict__ bnsum, float* __restrict__ bnss) {
  __shared__ float lsum[4][64], lsq[4][64];
  int lane = threadIdx.x & 63;
  int wid = threadIdx.x >> 6;
  int el = lane & 15;  // channel group (8 ch)
  int st = lane >> 4;  // edge stream 0..3
  const float4 w0a = we[el * 2], w0b = we[el * 2 + 1];
  const float4 w1a = we[32 + el * 2], w1b = we[32 + el * 2 + 1];
  const float4 w2a = we[64 + el * 2], w2b = we[64 + el * 2 + 1];
  const float4 ava = att[el * 2], avb = att[el * 2 + 1];
  float4 rsa = {0, 0, 0, 0}, rsb = {0, 0, 0, 0};
  float4 rqa = {0, 0, 0, 0}, rqb = {0, 0, 0, 0};
  for (int v = blockIdx.x * 4 + wid; v < NN; v += gridDim.x * 4) {
    int b = off[v], e = off[v + 1];
    float4 xra = xr[(unsigned)(v * 32 + el * 2)];
    float4 xrb = xr[(unsigned)(v * 32 + el * 2 + 1)];
    float ssum = 0.0f;
    float4 acca = {0, 0, 0, 0}, accb = {0, 0, 0, 0};
    int ng = (e - b + 3) >> 2;
    int jj = b + st;
    float4 pa = ces[(unsigned)jj];
    uint4 ua = xlb[(unsigned)(__float_as_int(pa.w) * 16 + el)];
    float4 qa = ces[(unsigned)(jj + 4)];
    for (int g = 0; g < ng; g++) {
      uint4 nua = xlb[(unsigned)(__float_as_int(qa.w) * 16 + el)];
      float4 ta = ces[(unsigned)(jj + 8)];
      float4 ra, rb;
      ra.x = bf_lo(ua.x); ra.y = bf_hi(ua.x); ra.z = bf_lo(ua.y); ra.w = bf_hi(ua.y);
      rb.x = bf_lo(ua.z); rb.y = bf_hi(ua.z); rb.z = bf_lo(ua.w); rb.w = bf_hi(ua.w);
      float4 ma, mb;
      ma.x = ra.x + xra.x + pa.x * w0a.x + pa.y * w1a.x + pa.z * w2a.x;
      ma.y = ra.y + xra.y + pa.x * w0a.y + pa.y * w1a.y + pa.z * w2a.y;
      ma.z = ra.z + xra.z + pa.x * w0a.z + pa.y * w1a.z + pa.z * w2a.z;
      ma.w = ra.w + xra.w + pa.x * w0a.w + pa.y * w1a.w + pa.z * w2a.w;
      mb.x = rb.x + xrb.x + pa.x * w0b.x + pa.y * w1b.x + pa.z * w2b.x;
      mb.y = rb.y + xrb.y + pa.x * w0b.y + pa.y * w1b.y + pa.z * w2b.y;
      mb.z = rb.z + xrb.z + pa.x * w0b.z + pa.y * w1b.z + pa.z * w2b.z;
      mb.w = rb.w + xrb.w + pa.x * w0b.w + pa.y * w1b.w + pa.z * w2b.w;
      ma.x = fmaxf(ma.x, 0.2f * ma.x); ma.y = fmaxf(ma.y, 0.2f * ma.y);
      ma.z = fmaxf(ma.z, 0.2f * ma.z); ma.w = fmaxf(ma.w, 0.2f * ma.w);
      mb.x = fmaxf(mb.x, 0.2f * mb.x); mb.y = fmaxf(mb.y, 0.2f * mb.y);
      mb.z = fmaxf(mb.z, 0.2f * mb.z); mb.w = fmaxf(mb.w, 0.2f * mb.w);
      float l = ma.x * ava.x + ma.y * ava.y + ma.z * ava.z + ma.w * ava.w +
                mb.x * avb.x + mb.y * avb.y + mb.z * avb.z + mb.w * avb.w;
      l += __shfl_xor(l, 1, 64);
      l += __shfl_xor(l, 2, 64);
      l += __shfl_xor(l, 4, 64);  // per-head logit (8-lane groups)
      float p = (jj < e) ? __expf(l) : 0.0f;
      ssum += p;
      acca.x += p * ra.x; acca.y += p * ra.y; acca.z += p * ra.z; acca.w += p * ra.w;
      accb.x += p * rb.x; accb.y += p * rb.y; accb.z += p * rb.z; accb.w += p * rb.w;
      jj += 4;
      pa = qa; ua = nua; qa = ta;
    }
    // combine the 4 streams (masks 16, 32)
#pragma unroll
    for (int m = 16; m <= 32; m <<= 1) {
      ssum += __shfl_xor(ssum, m, 64);
      acca.x += __shfl_xor(acca.x, m, 64); acca.y += __shfl_xor(acca.y, m, 64);
      acca.z += __shfl_xor(acca.z, m, 64); acca.w += __shfl_xor(acca.w, m, 64);
      accb.x += __shfl_xor(accb.x, m, 64); accb.y += __shfl_xor(accb.y, m, 64);
      accb.z += __shfl_xor(accb.z, m, 64); accb.w += __shfl_xor(accb.w, m, 64);
    }
    float inv = 1.0f / (ssum + 1e-16f);
    float4 oa = {acca.x * inv, acca.y * inv, acca.z * inv, acca.w * inv};
    float4 ob = {accb.x * inv, accb.y * inv, accb.z * inv, accb.w * inv};
    // head mean: partner el^8 holds the other head's same channels
    float pax = __shfl_xor(oa.x, 8, 64), pay = __shfl_xor(oa.y, 8, 64);
    float paz = __shfl_xor(oa.z, 8, 64), paw = __shfl_xor(oa.w, 8, 64);
    float pbx = __shfl_xor(ob.x, 8, 64), pby = __shfl_xor(ob.y, 8, 64);
    float pbz = __shfl_xor(ob.z, 8, 64), pbw = __shfl_xor(ob.w, 8, 64);
    if (lane < 8) {  // st==0, el<8: channels el*8..el*8+7
      float4 bva = bias[el * 2], bvb = bias[el * 2 + 1];
      float4 va = {0.5f * (oa.x + pax) + bva.x, 0.5f * (oa.y + pay) + bva.y,
                   0.5f * (oa.z + paz) + bva.z, 0.5f * (oa.w + paw) + bva.w};
      float4 vb = {0.5f * (ob.x + pbx) + bvb.x, 0.5f * (ob.y + pby) + bvb.y,
                   0.5f * (ob.z + pbz) + bvb.z, 0.5f * (ob.w + pbw) + bvb.w};
      hout[(unsigned)(v * 16 + el * 2)] = va;
      hout[(unsigned)(v * 16 + el * 2 + 1)] = vb;
      rsa.x += va.x; rsa.y += va.y; rsa.z += va.z; rsa.w += va.w;
      rsb.x += vb.x; rsb.y += vb.y; rsb.z += vb.z; rsb.w += vb.w;
      rqa.x += va.x * va.x; rqa.y += va.y * va.y; rqa.z += va.z * va.z; rqa.w += va.w * va.w;
      rqb.x += vb.x * vb.x; rqb.y += vb.y * vb.y; rqb.z += vb.z * vb.z; rqb.w += vb.w * vb.w;
    }
  }
  if (lane < 8) {
    lsum[wid][el * 8 + 0] = rsa.x; lsum[wid][el * 8 + 1] = rsa.y;
    lsum[wid][el * 8 + 2] = rsa.z; lsum[wid][el * 8 + 3] = rsa.w;
    lsum[wid][el * 8 + 4] = rsb.x; lsum[wid][el * 8 + 5] = rsb.y;
    lsum[wid][el * 8 + 6] = rsb.z; lsum[wid][el * 8 + 7] = rsb.w;
    lsq[wid][el * 8 + 0] = rqa.x; lsq[wid][el * 8 + 1] = rqa.y;
    lsq[wid][el * 8 + 2] = rqa.z; lsq[wid][el * 8 + 3] = rqa.w;
    lsq[wid][el * 8 + 4] = rqb.x; lsq[wid][el * 8 + 5] = rqb.y;
    lsq[wid][el * 8 + 6] = rqb.z; lsq[wid][el * 8 + 7] = rqb.w;
  }
  __syncthreads();
  if (threadIdx.x < 64) {
    float a = lsum[0][threadIdx.x] + lsum[1][threadIdx.x] + lsum[2][threadIdx.x] +
              lsum[3][threadIdx.x];
    float q = lsq[0][threadIdx.x] + lsq[1][threadIdx.x] + lsq[2][threadIdx.x] +
              lsq[3][threadIdx.x];
    atomicAdd(&bnsum[threadIdx.x], a);
    atomicAdd(&bnss[threadIdx.x], q);
  }
}

// HC=64: 4 ch/lane (uint2 bf16). head0 = el 0..7.
__global__ void k_gat64(const int* __restrict__ off, const float4* __restrict__ ces,
                        const uint2* __restrict__ xlb, const float4* __restrict__ xr,
                        const float4* __restrict__ we, const float4* __restrict__ att,
                        const float4* __restrict__ bias, float4* __restrict__ hout,
                        float* __restrict__ bnsum, float* __restrict__ bnss) {
  __shared__ float lsum[4][32], lsq[4][32];
  int lane = threadIdx.x & 63;
  int wid = threadIdx.x >> 6;
  int el = lane & 15;  // channel group (4 ch)
  int st = lane >> 4;  // edge stream 0..3
  const float4 w0 = we[el], w1 = we[16 + el], w2 = we[32 + el];
  const float4 av = att[el];
  float4 rs = {0, 0, 0, 0}, rq = {0, 0, 0, 0};
  for (int v = blockIdx.x * 4 + wid; v < NN; v += gridDim.x * 4) {
    int b = off[v], e = off[v + 1];
    float4 xrv = xr[(unsigned)(v * 16 + el)];
    float ssum = 0.0f;
    float4 acc = {0, 0, 0, 0};
    int ng = (e - b + 3) >> 2;
    int jj = b + st;
    float4 pa = ces[(unsigned)jj];
    uint2 ua = xlb[(unsigned)(__float_as_int(pa.w) * 16 + el)];
    float4 qa = ces[(unsigned)(jj + 4)];
    for (int g = 0; g < ng; g++) {
      uint2 nua = xlb[(unsigned)(__float_as_int(qa.w) * 16 + el)];
      float4 ta = ces[(unsigned)(jj + 8)];
      float4 ra;
      ra.x = bf_lo(ua.x); ra.y = bf_hi(ua.x); ra.z = bf_lo(ua.y); ra.w = bf_hi(ua.y);
      float4 ma;
      ma.x = ra.x + xrv.x + pa.x * w0.x + pa.y * w1.x + pa.z * w2.x;
      ma.y = ra.y + xrv.y + pa.x * w0.y + pa.y * w1.y + pa.z * w2.y;
      ma.z = ra.z + xrv.z + pa.x * w0.z + pa.y * w1.z + pa.z * w2.z;
      ma.w = ra.w + xrv.w + pa.x * w0.w + pa.y * w1.w + pa.z * w2.w;
      ma.x = fmaxf(ma.x, 0.2f * ma.x); ma.y = fmaxf(ma.y, 0.2f * ma.y);
      ma.z = fmaxf(ma.z, 0.2f * ma.z); ma.w = fmaxf(ma.w, 0.2f * ma.w);
      float l = ma.x * av.x + ma.y * av.y + ma.z * av.z + ma.w * av.w;
      l += __shfl_xor(l, 1, 64);
      l += __shfl_xor(l, 2, 64);
      l += __shfl_xor(l, 4, 64);  // per-head logit (8-lane groups)
      float p = (jj < e) ? __expf(l) : 0.0f;
      ssum += p;
      acc.x += p * ra.x; acc.y += p * ra.y; acc.z += p * ra.z; acc.w += p * ra.w;
      jj += 4;
      pa = qa; ua = nua; qa = ta;
    }
#pragma unroll
    for (int m = 16; m <= 32; m <<= 1) {
      ssum += __shfl_xor(ssum, m, 64);
      acc.x += __shfl_xor(acc.x, m, 64); acc.y += __shfl_xor(acc.y, m, 64);
      acc.z += __shfl_xor(acc.z, m, 64); acc.w += __shfl_xor(acc.w, m, 64);
    }
    float inv = 1.0f / (ssum + 1e-16f);
    float4 o = {acc.x * inv, acc.y * inv, acc.z * inv, acc.w * inv};
    float px = __shfl_xor(o.x, 8, 64), py = __shfl_xor(o.y, 8, 64);
    float pz = __shfl_xor(o.z, 8, 64), pw = __shfl_xor(o.w, 8, 64);
    if (lane < 8) {  // st==0, el<8: channels el*4..el*4+3
      float4 bv = bias[el];
      float4 val = {0.5f * (o.x + px) + bv.x, 0.5f * (o.y + py) + bv.y,
                    0.5f * (o.z + pz) + bv.z, 0.5f * (o.w + pw) + bv.w};
      hout[(unsigned)(v * 8 + el)] = val;
      rs.x += val.x; rs.y += val.y; rs.z += val.z; rs.w += val.w;
      rq.x += val.x * val.x; rq.y += val.y * val.y;
      rq.z += val.z * val.z; rq.w += val.w * val.w;
    }
  }
  if (lane < 8) {
    lsum[wid][el * 4 + 0] = rs.x; lsum[wid][el * 4 + 1] = rs.y;
    lsum[wid][el * 4 + 2] = rs.z; lsum[wid][el * 4 + 3] = rs.w;
    lsq[wid][el * 4 + 0] = rq.x; lsq[wid][el * 4 + 1] = rq.y;
    lsq[wid][el * 4 + 2] = rq.z; lsq[wid][el * 4 + 3] = rq.w;
  }
  __syncthreads();
  if (threadIdx.x < 32) {
    float a = lsum[0][threadIdx.x] + lsum[1][threadIdx.x] + lsum[2][threadIdx.x] +
              lsum[3][threadIdx.x];
    float q = lsq[0][threadIdx.x] + lsq[1][threadIdx.x] + lsq[2][threadIdx.x] +
              lsq[3][threadIdx.x];
    atomicAdd(&bnsum[threadIdx.x], a);
    atomicAdd(&bnss[threadIdx.x], q);
  }
}

// ---------------- pooling (fused BN2+ELU) + head ----------------
__global__ void k_goffbs(const int* __restrict__ batch, int* __restrict__ goff) {
  int g = threadIdx.x;  // 512 threads
  int lo = 0, hi = NN;
  while (lo < hi) {
    int mid = (lo + hi) >> 1;
    if (batch[mid] < g) lo = mid + 1; else hi = mid;
  }
  goff[g] = lo;
  if (g == 0) goff[GG] = NN;
}

__global__ void k_pool(const float* __restrict__ h2, const int* __restrict__ goff,
                       const float* __restrict__ bnsum, const float* __restrict__ bnss,
                       const float* __restrict__ g, const float* __restrict__ be,
                       float* __restrict__ pooled) {
  int gi = blockIdx.x, c = threadIdx.x;  // 64 threads
  float mu = bnsum[c] * (1.0f / NN);
  float var = bnss[c] * (1.0f / NN) - mu * mu;
  float is = rsqrtf(var + BN_EPS) * g[c];
  float sh = be[c] - mu * is;
  int s = goff[gi], n = goff[gi + 1] - s;
  float acc = 0.0f;
  int i = 0;
  for (; i + 4 <= n; i += 4) {  // 4 independent loads in flight
    float y0 = h2[(size_t)(s + i) * 64 + c];
    float y1 = h2[(size_t)(s + i + 1) * 64 + c];
    float y2 = h2[(size_t)(s + i + 2) * 64 + c];
    float y3 = h2[(size_t)(s + i + 3) * 64 + c];
    y0 = y0 * is + sh; y1 = y1 * is + sh; y2 = y2 * is + sh; y3 = y3 * is + sh;
    y0 = (y0 > 0.0f) ? y0 : (__expf(y0) - 1.0f);
    y1 = (y1 > 0.0f) ? y1 : (__expf(y1) - 1.0f);
    y2 = (y2 > 0.0f) ? y2 : (__expf(y2) - 1.0f);
    y3 = (y3 > 0.0f) ? y3 : (__expf(y3) - 1.0f);
    acc += (y0 + y1) + (y2 + y3);
  }
  for (; i < n; i++) {
    float y = h2[(size_t)(s + i) * 64 + c] * is + sh;
    y = (y > 0.0f) ? y : (__expf(y) - 1.0f);
    acc += y;
  }
  pooled[gi * 64 + c] = acc / fmaxf((float)n, 1.0f);
}

__global__ void k_fc1(const float* __restrict__ pooled, const float* __restrict__ w,
                      const float* __restrict__ b, float* __restrict__ t1) {
  int i = blockIdx.x * blockDim.x + threadIdx.x;  // 16384
  int g = i >> 5, o = i & 31;
  float acc = b[o];
#pragma unroll 8
  for (int k = 0; k < 64; k++) acc += pooled[g * 64 + k] * w[k * 32 + o];
  t1[i] = acc;
}

__global__ void k_head(const float* __restrict__ t1, const float* __restrict__ g3,
                       const float* __restrict__ be3, const float* __restrict__ fc2w,
                       const float* __restrict__ fc2b, float* __restrict__ out) {
  __shared__ float ssum[32], ssq[32], smu[32], sinv[32];
  int t = threadIdx.x;  // 512 threads, one per graph
  if (t < 32) {
    ssum[t] = 0.0f;
    ssq[t] = 0.0f;
  }
  __syncthreads();
  float y[32];
#pragma unroll
  for (int o = 0; o < 32; o++) y[o] = t1[t * 32 + o];
#pragma unroll
  for (int o = 0; o < 32; o++) {
    atomicAdd(&ssum[o], y[o]);
    atomicAdd(&ssq[o], y[o] * y[o]);
  }
  __syncthreads();
  if (t < 32) {
    float mu = ssum[t] * (1.0f / GG);
    float var = ssq[t] * (1.0f / GG) - mu * mu;
    smu[t] = mu;
    sinv[t] = rsqrtf(var + BN_EPS);
  }
  __syncthreads();
  float acc = fc2b[0];
#pragma unroll
  for (int o = 0; o < 32; o++) {
    float yy = (y[o] - smu[o]) * sinv[o] * g3[o] + be3[o];
    yy = (yy > 0.0f) ? yy : (__expf(yy) - 1.0f);
    acc += yy * fc2w[o];
  }
  out[t] = 1.0f / (1.0f + __expf(-acc));
}

// ---------------- launch ----------------
extern "C" void kernel_launch(void* const* d_in, const int* in_sizes, int n_in,
                              void* d_out, int out_size, void* d_ws, size_t ws_size,
                              hipStream_t stream) {
  const float* x = (const float*)d_in[0];
  const float* ea = (const float*)d_in[1];
  const float* w1l = (const float*)d_in[2];
  const float* b1l = (const float*)d_in[3];
  const float* w1r = (const float*)d_in[4];
  const float* b1r = (const float*)d_in[5];
  const float* w1e = (const float*)d_in[6];
  const float* att1 = (const float*)d_in[7];
  const float* bias1 = (const float*)d_in[8];
  const float* g1 = (const float*)d_in[9];
  const float* be1 = (const float*)d_in[10];
  const float* w2l = (const float*)d_in[11];
  const float* b2l = (const float*)d_in[12];
  const float* w2r = (const float*)d_in[13];
  const float* b2r = (const float*)d_in[14];
  const float* w2e = (const float*)d_in[15];
  const float* att2 = (const float*)d_in[16];
  const float* bias2 = (const float*)d_in[17];
  const float* g2 = (const float*)d_in[18];
  const float* be2 = (const float*)d_in[19];
  const float* fc1w = (const float*)d_in[20];
  const float* fc1b = (const float*)d_in[21];
  const float* g3 = (const float*)d_in[22];
  const float* be3 = (const float*)d_in[23];
  const float* fc2w = (const float*)d_in[24];
  const float* fc2b = (const float*)d_in[25];
  const int* ei = (const int*)d_in[26];
  const int* batch = (const int*)d_in[27];
  float* out = (float*)d_out;

  char* w = (char*)d_ws;
  size_t off = 0;
  auto alloc = [&](size_t bytes) {
    size_t r = off;
    off += (bytes + 255) & ~(size_t)255;
    return r;
  };
  // zero-init region (one memset)
  int* cnt = (int*)(w + alloc(NN * 4));
  float* bn1sum = (float*)(w + alloc(32 * 4));
  float* bn1ss = (float*)(w + alloc(32 * 4));
  float* bn2sum = (float*)(w + alloc(64 * 4));
  float* bn2ss = (float*)(w + alloc(64 * 4));
  size_t zero_bytes = off;
  // rest
  int* rank = (int*)(w + alloc((size_t)EE * 4));
  int* csr_off = (int*)(w + alloc((size_t)(NN + 1) * 4));
  int* bsum = (int*)(w + alloc(512 * 4));
  int* goff = (int*)(w + alloc((size_t)(GG + 1) * 4));
  float4* ces = (float4*)(w + alloc((size_t)(ET + 16) * 16));  // +16 pad slots
  unsigned short* xlb = (unsigned short*)(w + alloc((size_t)NN * 128 * 2));
  float* xr = (float*)(w + alloc((size_t)NN * 128 * 4));
  float* h1 = (float*)(w + alloc((size_t)NN * 32 * 4));
  float* h2 = (float*)(w + alloc((size_t)NN * 64 * 4));
  float* pooled = (float*)(w + alloc((size_t)GG * 64 * 4));
  float* t1 = (float*)(w + alloc((size_t)GG * 32 * 4));
  (void)ws_size;
  (void)in_sizes;
  (void)n_in;
  (void)out_size;

  hipMemsetAsync(d_ws, 0, zero_bytes, stream);

  // CSR build
  k_hist<<<EE / 256, 256, 0, stream>>>(ei, cnt, rank);
  k_scan_a<<<512, 256, 0, stream>>>(cnt, csr_off, bsum);
  k_scan_b<<<1, 512, 0, stream>>>(bsum);
  k_scan_c<<<512, 256, 0, stream>>>(csr_off, bsum);
  k_scatter<<<EE / 256, 256, 0, stream>>>(ei, ea, csr_off, rank, ces);
  k_selfslot<<<NN / 16, 256, 0, stream>>>(csr_off, ces);

  // layer 1 (HC=64, C=32)
  k_lin<64, 64, false><<<2048, 256, 0, stream>>>(x, w1l, b1l, w1r, b1r, xlb, xr,
                                                 nullptr, nullptr, nullptr, nullptr);
  k_gat64<<<2048, 256, 0, stream>>>(csr_off, ces, (const uint2*)xlb,
                                    (const float4*)xr, (const float4*)w1e,
                                    (const float4*)att1, (const float4*)bias1,
                                    (float4*)h1, bn1sum, bn1ss);

  // layer 2 (HC=128, C=64) — BN1+ELU fused into the staging load
  k_lin<32, 128, true><<<2048, 256, 0, stream>>>(h1, w2l, b2l, w2r, b2r, xlb, xr,
                                                 bn1sum, bn1ss, g1, be1);
  k_gat128<<<2048, 256, 0, stream>>>(csr_off, ces, (const uint4*)xlb,
                                     (const float4*)xr, (const float4*)w2e,
                                     (const float4*)att2, (const float4*)bias2,
                                     (float4*)h2, bn2sum, bn2ss);

  // pooling (BN2+ELU fused) + head
  k_goffbs<<<1, GG, 0, stream>>>(batch, goff);
  k_pool<<<GG, 64, 0, stream>>>(h2, goff, bn2sum, bn2ss, g2, be2, pooled);
  k_fc1<<<64, 256, 0, stream>>>(pooled, fc1w, fc1b, t1);
  k_head<<<1, GG, 0, stream>>>(t1, g3, be3, fc2w, fc2b, out);
}